// Round 19
// baseline (1098.451 us; speedup 1.0000x reference)
//
#include <hip/hip_runtime.h>
#include <hip/hip_bf16.h>
#include <math.h>

#define HID 256
#define NH 8
#define DH 32
#define NL 2
#define NV 20000
#define NT 50000
#define NE 100000
#define NC 8
#define FIN 64

typedef unsigned short u16;
typedef unsigned int u32;
typedef short s16x8 __attribute__((ext_vector_type(8)));
typedef float f32x4 __attribute__((ext_vector_type(4)));

__device__ __forceinline__ float bf2f(u16 u) { return __uint_as_float(((u32)u) << 16); }
__device__ __forceinline__ u16 f2bf(float f) {
    u32 x = __float_as_uint(f);
    u32 r = ((x >> 16) & 1u) + 0x7fffu;
    return (u16)((x + r) >> 16);
}
__device__ __forceinline__ void up2(u32 u, float& a, float& b) {
    a = __uint_as_float(u << 16);
    b = __uint_as_float(u & 0xffff0000u);
}
__device__ __forceinline__ s16x8 gelu8(s16x8 a) {
    s16x8 r;
#pragma unroll
    for (int i = 0; i < 8; i++) {
        float v = bf2f((u16)a[i]);
        v = 0.5f * v * (1.f + erff(v * 0.70710678118654752f));
        r[i] = (short)f2bf(v);
    }
    return r;
}

// ---------------- zero fill ----------------
__global__ void k_zero_i(int* __restrict__ p, int n) {
    for (int i = blockIdx.x * 256 + threadIdx.x; i < n; i += gridDim.x * 256) p[i] = 0;
}

// ---------------- batched histogram of 3 dst arrays ----------------
__global__ void k_hist3(const int* __restrict__ d0, const int* __restrict__ d1, const int* __restrict__ d2,
                        int* __restrict__ cnt3) {
    int r = blockIdx.x >> 9;        // 0..2
    int b = blockIdx.x & 511;
    const int* dst = (r == 0) ? d0 : (r == 1) ? d1 : d2;
    int* cnt = cnt3 + (size_t)r * NT;
    for (int e = b * 256 + threadIdx.x; e < NE; e += 512 * 256)
        atomicAdd(&cnt[dst[e]], 1);
}

// ---------------- batched serial scans: 3 blocks, one per relation (run concurrently) ------
__global__ __launch_bounds__(1024) void k_scan3(const int* __restrict__ cnt3,
                                                int* __restrict__ rp0, int* __restrict__ rp1, int* __restrict__ rp2) {
    int r = blockIdx.x;
    const int* cnt = cnt3 + (size_t)r * NT;
    int* rp = (r == 0) ? rp0 : (r == 1) ? rp1 : rp2;
    int n = (r == 1) ? NV : NT;
    __shared__ int wsum[16];
    __shared__ int carry_s;
    int t = threadIdx.x, lane = t & 63, wv = t >> 6;
    if (t == 0) { carry_s = 0; rp[0] = 0; }
    __syncthreads();
    for (int base = 0; base < n; base += 1024) {
        int v = (base + t < n) ? cnt[base + t] : 0;
        int x = v;
#pragma unroll
        for (int off = 1; off < 64; off <<= 1) {
            int y = __shfl_up(x, off, 64);
            if (lane >= off) x += y;
        }
        if (lane == 63) wsum[wv] = x;
        __syncthreads();
        if (wv == 0 && lane < 16) {
            int s = wsum[lane];
#pragma unroll
            for (int off = 1; off < 16; off <<= 1) {
                int y = __shfl_up(s, off, 64);
                if (lane >= off) s += y;
            }
            wsum[lane] = s;
        }
        __syncthreads();
        int prefix = carry_s + (wv > 0 ? wsum[wv - 1] : 0);
        if (base + t < n) rp[base + t + 1] = prefix + x;
        __syncthreads();
        if (t == 0) carry_s += wsum[15];
        __syncthreads();
    }
}

// ---------------- batched fill copy: fill3[r][i] = rp_r[i] ----------------
__global__ void k_copy3(const int* __restrict__ rp0, const int* __restrict__ rp1, const int* __restrict__ rp2,
                        int* __restrict__ fill3) {
    int r = blockIdx.x >> 8;
    int b = blockIdx.x & 255;
    const int* rp = (r == 0) ? rp0 : (r == 1) ? rp1 : rp2;
    int n = (r == 1) ? NV : NT;
    int* fill = fill3 + (size_t)r * NT;
    for (int i = b * 256 + threadIdx.x; i < n; i += 256 * 256) fill[i] = rp[i];
}

// ---------------- batched scatter ----------------
__global__ void k_scatter3(const int* __restrict__ d0, const int* __restrict__ s0,
                           const int* __restrict__ d1, const int* __restrict__ s1,
                           const int* __restrict__ d2, const int* __restrict__ s2,
                           int* __restrict__ fill3,
                           int* __restrict__ es0, int* __restrict__ es1, int* __restrict__ es2) {
    int r = blockIdx.x >> 9;
    int b = blockIdx.x & 511;
    const int* dst = (r == 0) ? d0 : (r == 1) ? d1 : d2;
    const int* src = (r == 0) ? s0 : (r == 1) ? s1 : s2;
    int* fill = fill3 + (size_t)r * NT;
    int* es = (r == 0) ? es0 : (r == 1) ? es1 : es2;
    for (int e = b * 256 + threadIdx.x; e < NE; e += 512 * 256) {
        int d = dst[e];
        int p = atomicAdd(&fill[d], 1);
        es[p] = src[e];
    }
}

// ---------------- input projection ----------------
__global__ __launch_bounds__(256) void k_in_proj(const float* __restrict__ X, const float* __restrict__ W,
                          const float* __restrict__ b, u16* __restrict__ Y, int N) {
    const int NPB = 16;
    __shared__ float xs[NPB][FIN];
    int n0 = blockIdx.x * NPB;
    int t = threadIdx.x;
    for (int idx = t; idx < NPB * FIN; idx += 256) {
        int i = idx >> 6, c = idx & 63;
        int n = n0 + i;
        xs[i][c] = (n < N) ? X[(size_t)n * FIN + c] : 0.f;
    }
    __syncthreads();
    float acc[NPB];
#pragma unroll
    for (int i = 0; i < NPB; i++) acc[i] = 0.f;
    for (int c = 0; c < FIN; c++) {
        float w = W[c * HID + t];
#pragma unroll
        for (int i = 0; i < NPB; i++) acc[i] += xs[i][c] * w;
    }
    float bb = b[t];
    for (int i = 0; i < NPB; i++) {
        int n = n0 + i;
        if (n < N) Y[(size_t)n * HID + t] = f2bf(fmaxf(acc[i] + bb, 0.f));
    }
}

// swizzle index for MFMA B fragment: given (k,n) -> flat idx in Wsw
__device__ __forceinline__ int swz_idx(int k, int n) {
    int ks = k >> 5, r = k & 31;
    int j = r & 7;
    int l = ((r >> 3) << 4) | (n & 15);
    int nt = n >> 4;
    return ((ks * 16 + nt) * 64 + l) * 8 + j;
}

// ---------------- fuse rel matrix into projection weight, emit SWIZZLED bf16 ----------------
__global__ __launch_bounds__(256) void k_fuse_w(const float* __restrict__ W, const float* __restrict__ b,
                        const float* __restrict__ R, u16* __restrict__ Wsw, float* __restrict__ bout) {
    int h = blockIdx.x; // 8 blocks
    __shared__ float sR[DH * DH];
    int t = threadIdx.x;
    for (int idx = t; idx < DH * DH; idx += 256) sR[idx] = R[h * DH * DH + idx];
    __syncthreads();
    int f = t & 31, c0 = t >> 5;
    for (int c = c0; c < HID; c += 8) {
        float acc = 0.f;
#pragma unroll
        for (int d = 0; d < DH; d++) acc += W[c * HID + h * DH + d] * sR[d * DH + f];
        Wsw[swz_idx(c, h * DH + f)] = f2bf(acc);
    }
    if (t < DH) {
        float acc = 0.f;
#pragma unroll
        for (int d = 0; d < DH; d++) acc += b[h * DH + d] * sR[d * DH + t];
        bout[h * DH + t] = acc;
    }
}

// ---------------- batched swizzle of 9 static weights: Wq[0..3], Wa[0..3], Ws1 ----------------
__global__ __launch_bounds__(256) void k_swz_multi(const float* __restrict__ Wq, const float* __restrict__ Wa,
                                                   const float* __restrict__ Ws1, u16* __restrict__ out) {
    int slot = blockIdx.x >> 8;
    int idx = ((blockIdx.x & 255) << 8) | threadIdx.x; // 0..65535
    const float* src = (slot < 4) ? (Wq + (size_t)slot * 65536)
                     : (slot < 8) ? (Wa + (size_t)(slot - 4) * 65536)
                                  : Ws1;
    int j = idx & 7, l = (idx >> 3) & 63, nt = (idx >> 9) & 15, ks = idx >> 13;
    int k = ks * 32 + (l >> 4) * 8 + j;
    int n = nt * 16 + (l & 15);
    out[(size_t)slot * 65536 + idx] = f2bf(src[k * HID + n]);
}

// ---------------- MFMA GEMM, slim-wave ----------------
// MODE 0: bf16+bias. MODE 1: f32, no bias. MODE 2: skip-mix bf16. MODE 3: bf16, no bias.
template <int MODE, int GELU>
__global__ __launch_bounds__(256) void k_mm(const u16* __restrict__ X, const u16* __restrict__ Wsw,
                                            const float* __restrict__ bias, void* __restrict__ Y,
                                            const float* __restrict__ skip_, int N) {
    int tid = threadIdx.x;
    int w = tid >> 6, lane = tid & 63;
    int r0 = blockIdx.x * 16;
    int rA = r0 + (lane & 15);
    int koffg = lane >> 4;
    s16x8 a[8];
    if (rA < N) {
        const s16x8* ap = (const s16x8*)(X + (size_t)rA * HID) + koffg;
#pragma unroll
        for (int ks = 0; ks < 8; ks++) a[ks] = ap[ks * 4];
    } else {
#pragma unroll
        for (int ks = 0; ks < 8; ks++) a[ks] = (s16x8){0, 0, 0, 0, 0, 0, 0, 0};
    }
    if (GELU) {
#pragma unroll
        for (int ks = 0; ks < 8; ks++) a[ks] = gelu8(a[ks]);
    }
    f32x4 acc[4];
#pragma unroll
    for (int nt = 0; nt < 4; nt++) acc[nt] = (f32x4){0.f, 0.f, 0.f, 0.f};
    const s16x8* wp = (const s16x8*)Wsw;
#pragma unroll
    for (int ks = 0; ks < 8; ks++) {
        const s16x8* wq = wp + (size_t)ks * 16 * 64 + lane;
#pragma unroll
        for (int nt = 0; nt < 4; nt++) {
            s16x8 b = wq[(w * 4 + nt) * 64];
            acc[nt] = __builtin_amdgcn_mfma_f32_16x16x32_bf16(a[ks], b, acc[nt], 0, 0, 0);
        }
    }
    int colb = lane & 15;
    int rowb = r0 + koffg * 4;
    float beta = 0.f, ombeta = 0.f;
    if (MODE == 2) { beta = 1.f / (1.f + expf(-skip_[0])); ombeta = 1.f - beta; }
#pragma unroll
    for (int nt = 0; nt < 4; nt++) {
        int col = w * 64 + nt * 16 + colb;
        float bb = (MODE == 1 || MODE == 3) ? 0.f : bias[col];
#pragma unroll
        for (int j = 0; j < 4; j++) {
            int row = rowb + j;
            if (row < N) {
                float v = acc[nt][j] + bb;
                if (MODE == 0 || MODE == 3) {
                    ((u16*)Y)[(size_t)row * HID + col] = f2bf(v);
                } else if (MODE == 1) {
                    ((float*)Y)[(size_t)row * HID + col] = v;
                } else {
                    u16* hp = (u16*)Y + (size_t)row * HID + col;
                    *hp = f2bf(beta * v + ombeta * bf2f(*hp));
                }
            }
        }
    }
}

// ---------------- dual-B slim-wave MFMA GEMM (A loaded once) ----------------
__global__ __launch_bounds__(256) void k_mm2(const u16* __restrict__ X,
                                             const u16* __restrict__ W1, const float* __restrict__ b1, u16* __restrict__ Y1,
                                             const u16* __restrict__ W2, const float* __restrict__ b2, u16* __restrict__ Y2,
                                             int N) {
    int tid = threadIdx.x;
    int w = tid >> 6, lane = tid & 63;
    int r0 = blockIdx.x * 16;
    int rA = r0 + (lane & 15);
    int koffg = lane >> 4;
    s16x8 a[8];
    if (rA < N) {
        const s16x8* ap = (const s16x8*)(X + (size_t)rA * HID) + koffg;
#pragma unroll
        for (int ks = 0; ks < 8; ks++) a[ks] = ap[ks * 4];
    } else {
#pragma unroll
        for (int ks = 0; ks < 8; ks++) a[ks] = (s16x8){0, 0, 0, 0, 0, 0, 0, 0};
    }
    int colb = lane & 15;
    int rowb = r0 + koffg * 4;
#pragma unroll
    for (int pass = 0; pass < 2; pass++) {
        const u16* Wsw = pass ? W2 : W1;
        const float* bias = pass ? b2 : b1;
        u16* Y = pass ? Y2 : Y1;
        f32x4 acc[4];
#pragma unroll
        for (int nt = 0; nt < 4; nt++) acc[nt] = (f32x4){0.f, 0.f, 0.f, 0.f};
        const s16x8* wp = (const s16x8*)Wsw;
#pragma unroll
        for (int ks = 0; ks < 8; ks++) {
            const s16x8* wq = wp + (size_t)ks * 16 * 64 + lane;
#pragma unroll
            for (int nt = 0; nt < 4; nt++) {
                s16x8 b = wq[(w * 4 + nt) * 64];
                acc[nt] = __builtin_amdgcn_mfma_f32_16x16x32_bf16(a[ks], b, acc[nt], 0, 0, 0);
            }
        }
#pragma unroll
        for (int nt = 0; nt < 4; nt++) {
            int col = w * 64 + nt * 16 + colb;
            float bb = bias[col];
#pragma unroll
            for (int j = 0; j < 4; j++) {
                int row = rowb + j;
                if (row < N) Y[(size_t)row * HID + col] = f2bf(acc[nt][j] + bb);
            }
        }
    }
}

// ---------------- triple-B slim-wave MFMA GEMM: q + k + v from one A read ----------------
__global__ __launch_bounds__(256) void k_mm3(const u16* __restrict__ X,
                                             const u16* __restrict__ W0, const float* __restrict__ b0, u16* __restrict__ Y0,
                                             const u16* __restrict__ W1, const float* __restrict__ b1, u16* __restrict__ Y1,
                                             const u16* __restrict__ W2, const float* __restrict__ b2, u16* __restrict__ Y2,
                                             int N) {
    int tid = threadIdx.x;
    int w = tid >> 6, lane = tid & 63;
    int r0 = blockIdx.x * 16;
    int rA = r0 + (lane & 15);
    int koffg = lane >> 4;
    s16x8 a[8];
    if (rA < N) {
        const s16x8* ap = (const s16x8*)(X + (size_t)rA * HID) + koffg;
#pragma unroll
        for (int ks = 0; ks < 8; ks++) a[ks] = ap[ks * 4];
    } else {
#pragma unroll
        for (int ks = 0; ks < 8; ks++) a[ks] = (s16x8){0, 0, 0, 0, 0, 0, 0, 0};
    }
    int colb = lane & 15;
    int rowb = r0 + koffg * 4;
#pragma unroll
    for (int pass = 0; pass < 3; pass++) {
        const u16* Wsw = (pass == 0) ? W0 : (pass == 1) ? W1 : W2;
        const float* bias = (pass == 0) ? b0 : (pass == 1) ? b1 : b2;
        u16* Y = (pass == 0) ? Y0 : (pass == 1) ? Y1 : Y2;
        f32x4 acc[4];
#pragma unroll
        for (int nt = 0; nt < 4; nt++) acc[nt] = (f32x4){0.f, 0.f, 0.f, 0.f};
        const s16x8* wp = (const s16x8*)Wsw;
#pragma unroll
        for (int ks = 0; ks < 8; ks++) {
            const s16x8* wq = wp + (size_t)ks * 16 * 64 + lane;
#pragma unroll
            for (int nt = 0; nt < 4; nt++) {
                s16x8 b = wq[(w * 4 + nt) * 64];
                acc[nt] = __builtin_amdgcn_mfma_f32_16x16x32_bf16(a[ks], b, acc[nt], 0, 0, 0);
            }
        }
#pragma unroll
        for (int nt = 0; nt < 4; nt++) {
            int col = w * 64 + nt * 16 + colb;
            float bb = bias[col];
#pragma unroll
            for (int j = 0; j < 4; j++) {
                int row = rowb + j;
                if (row < N) Y[(size_t)row * HID + col] = f2bf(acc[nt][j] + bb);
            }
        }
    }
}

// ---------------- online-softmax over one CSR, 2-deep prefetch ----------------
__device__ __forceinline__ void attn_pass(const u16* __restrict__ kA, const u16* __restrict__ vM,
                                          const int* __restrict__ es, int jb, int je,
                                          float q0, float q1, float q2, float q3, float ph, int lane4,
                                          float& o0, float& o1, float& o2, float& o3) {
    float m = -INFINITY, ss = 0.f, a0 = 0.f, a1 = 0.f, a2 = 0.f, a3 = 0.f;
    uint2 ku0 = {0, 0}, vu0 = {0, 0}, ku1 = {0, 0}, vu1 = {0, 0};
    if (jb < je) {
        int s = es[jb];
        ku0 = *(const uint2*)(kA + (size_t)s * HID + lane4);
        vu0 = *(const uint2*)(vM + (size_t)s * HID + lane4);
    }
    if (jb + 1 < je) {
        int s = es[jb + 1];
        ku1 = *(const uint2*)(kA + (size_t)s * HID + lane4);
        vu1 = *(const uint2*)(vM + (size_t)s * HID + lane4);
    }
    for (int j = jb; j < je; j++) {
        uint2 ku = ku0, vu = vu0;
        ku0 = ku1; vu0 = vu1;
        if (j + 2 < je) {
            int s = es[j + 2];
            ku1 = *(const uint2*)(kA + (size_t)s * HID + lane4);
            vu1 = *(const uint2*)(vM + (size_t)s * HID + lane4);
        }
        float k0, k1, k2, k3; up2(ku.x, k0, k1); up2(ku.y, k2, k3);
        float part = q0 * k0 + q1 * k1 + q2 * k2 + q3 * k3;
        part += __shfl_xor(part, 1, 64);
        part += __shfl_xor(part, 2, 64);
        part += __shfl_xor(part, 4, 64);
        float logit = part * ph;
        float nm = fmaxf(m, logit);
        float corr = expf(m - nm);
        float ee = expf(logit - nm);
        float v0, v1, v2, v3; up2(vu.x, v0, v1); up2(vu.y, v2, v3);
        ss = ss * corr + ee;
        a0 = a0 * corr + ee * v0; a1 = a1 * corr + ee * v1;
        a2 = a2 * corr + ee * v2; a3 = a3 * corr + ee * v3;
        m = nm;
    }
    float inv = 1.f / (ss + 1e-16f);
    o0 += a0 * inv; o1 += a1 * inv; o2 += a2 * inv; o3 += a3 * inv;
}

// ---------------- single-relation node attention ----------------
__global__ __launch_bounds__(256) void k_node_attn(
        const u16* __restrict__ q, const u16* __restrict__ kA, const u16* __restrict__ vM,
        const int* __restrict__ rp, const int* __restrict__ es,
        const float* __restrict__ P, float scale,
        u16* __restrict__ agg, int Nd) {
    int node = blockIdx.x * 4 + (threadIdx.x >> 6);
    if (node >= Nd) return;
    int lane = threadIdx.x & 63;
    float ph = P[lane >> 3] * scale;
    uint2 qu = *(const uint2*)(q + (size_t)node * HID + lane * 4);
    float q0, q1, q2, q3; up2(qu.x, q0, q1); up2(qu.y, q2, q3);
    float o0 = 0.f, o1 = 0.f, o2 = 0.f, o3 = 0.f;
    attn_pass(kA, vM, es, rp[node], rp[node + 1], q0, q1, q2, q3, ph, lane * 4, o0, o1, o2, o3);
    u16* ap = agg + (size_t)node * HID + lane * 4;
    ap[0] = f2bf(o0); ap[1] = f2bf(o1); ap[2] = f2bf(o2); ap[3] = f2bf(o3);
}

// ---------------- dual-relation node attention: fused interleaved loop (2x ILP) ----------------
__global__ __launch_bounds__(256) void k_node_attn2(
        const u16* __restrict__ q,
        const u16* __restrict__ kA0, const u16* __restrict__ vM0,
        const int* __restrict__ rp0, const int* __restrict__ es0, const float* __restrict__ P0,
        const u16* __restrict__ kA1, const u16* __restrict__ vM1,
        const int* __restrict__ rp1, const int* __restrict__ es1, const float* __restrict__ P1,
        float scale, u16* __restrict__ agg, int Nd) {
    int node = blockIdx.x * 4 + (threadIdx.x >> 6);
    if (node >= Nd) return;
    int lane = threadIdx.x & 63;
    int h = lane >> 3;
    int lane4 = lane * 4;
    float ph0 = P0[h] * scale, ph1 = P1[h] * scale;
    uint2 qu = *(const uint2*)(q + (size_t)node * HID + lane4);
    float q0, q1, q2, q3; up2(qu.x, q0, q1); up2(qu.y, q2, q3);

    int ja = rp0[node], ea = rp0[node + 1];
    int jb = rp1[node], eb = rp1[node + 1];
    float mA = -INFINITY, sA = 0.f, xA0 = 0.f, xA1 = 0.f, xA2 = 0.f, xA3 = 0.f;
    float mB = -INFINITY, sB = 0.f, xB0 = 0.f, xB1 = 0.f, xB2 = 0.f, xB3 = 0.f;
    uint2 kuA = {0, 0}, vuA = {0, 0}, kuB = {0, 0}, vuB = {0, 0};
    if (ja < ea) {
        int s = es0[ja];
        kuA = *(const uint2*)(kA0 + (size_t)s * HID + lane4);
        vuA = *(const uint2*)(vM0 + (size_t)s * HID + lane4);
    }
    if (jb < eb) {
        int s = es1[jb];
        kuB = *(const uint2*)(kA1 + (size_t)s * HID + lane4);
        vuB = *(const uint2*)(vM1 + (size_t)s * HID + lane4);
    }
    while (ja < ea || jb < eb) {
        // --- step relation A (r0) ---
        if (ja < ea) {
            uint2 ku = kuA, vu = vuA;
            if (ja + 1 < ea) {
                int s = es0[ja + 1];
                kuA = *(const uint2*)(kA0 + (size_t)s * HID + lane4);
                vuA = *(const uint2*)(vM0 + (size_t)s * HID + lane4);
            }
            float k0, k1, k2, k3; up2(ku.x, k0, k1); up2(ku.y, k2, k3);
            float part = q0 * k0 + q1 * k1 + q2 * k2 + q3 * k3;
            part += __shfl_xor(part, 1, 64);
            part += __shfl_xor(part, 2, 64);
            part += __shfl_xor(part, 4, 64);
            float logit = part * ph0;
            float nm = fmaxf(mA, logit);
            float corr = expf(mA - nm);
            float ee = expf(logit - nm);
            float v0, v1, v2, v3; up2(vu.x, v0, v1); up2(vu.y, v2, v3);
            sA = sA * corr + ee;
            xA0 = xA0 * corr + ee * v0; xA1 = xA1 * corr + ee * v1;
            xA2 = xA2 * corr + ee * v2; xA3 = xA3 * corr + ee * v3;
            mA = nm;
            ja++;
        }
        // --- step relation B (r2) --- independent chain, interleaves with A
        if (jb < eb) {
            uint2 ku = kuB, vu = vuB;
            if (jb + 1 < eb) {
                int s = es1[jb + 1];
                kuB = *(const uint2*)(kA1 + (size_t)s * HID + lane4);
                vuB = *(const uint2*)(vM1 + (size_t)s * HID + lane4);
            }
            float k0, k1, k2, k3; up2(ku.x, k0, k1); up2(ku.y, k2, k3);
            float part = q0 * k0 + q1 * k1 + q2 * k2 + q3 * k3;
            part += __shfl_xor(part, 1, 64);
            part += __shfl_xor(part, 2, 64);
            part += __shfl_xor(part, 4, 64);
            float logit = part * ph1;
            float nm = fmaxf(mB, logit);
            float corr = expf(mB - nm);
            float ee = expf(logit - nm);
            float v0, v1, v2, v3; up2(vu.x, v0, v1); up2(vu.y, v2, v3);
            sB = sB * corr + ee;
            xB0 = xB0 * corr + ee * v0; xB1 = xB1 * corr + ee * v1;
            xB2 = xB2 * corr + ee * v2; xB3 = xB3 * corr + ee * v3;
            mB = nm;
            jb++;
        }
    }
    float invA = 1.f / (sA + 1e-16f);
    float invB = 1.f / (sB + 1e-16f);
    u16* ap = agg + (size_t)node * HID + lane4;
    ap[0] = f2bf(xA0 * invA + xB0 * invB);
    ap[1] = f2bf(xA1 * invA + xB1 * invB);
    ap[2] = f2bf(xA2 * invA + xB2 * invB);
    ap[3] = f2bf(xA3 * invA + xB3 * invB);
}

// ---------------- vpart ----------------
__global__ void k_vpart(const u16* __restrict__ hv, const int* __restrict__ current,
                        const float* __restrict__ Ws1, const float* __restrict__ bs1,
                        float* __restrict__ vpart) {
    __shared__ float row[HID];
    int t = threadIdx.x;
    for (int c = 0; c < NC; c++) {
        int n = current[c * 2];
        row[t] = bf2f(hv[(size_t)n * HID + t]);
        __syncthreads();
        float acc = 0.f;
        for (int i = 0; i < HID; i++) acc += row[i] * Ws1[(size_t)(HID + i) * HID + t];
        vpart[c * HID + t] = acc + bs1[t];
        __syncthreads();
    }
}

// ---------------- final: tpart bf16 ----------------
__global__ __launch_bounds__(256) void k_final(const u16* __restrict__ tpart, const float* __restrict__ vpart,
                        const float* __restrict__ Ws2, const float* __restrict__ bs2,
                        float* __restrict__ out) {
    __shared__ float vp[NC * HID];
    int t = threadIdx.x;
    for (int idx = t; idx < NC * HID; idx += 256) vp[idx] = vpart[idx];
    __syncthreads();
    int lane = t & 63, w = t >> 6;
    float w20[4], w21[4];
#pragma unroll
    for (int i = 0; i < 4; i++) {
        w20[i] = Ws2[(lane + 64 * i) * 2 + 0];
        w21[i] = Ws2[(lane + 64 * i) * 2 + 1];
    }
    float b0 = bs2[0], b1 = bs2[1];
    for (int n = blockIdx.x * 4 + w; n < NT; n += gridDim.x * 4) {
        float tp[4];
#pragma unroll
        for (int i = 0; i < 4; i++) tp[i] = bf2f(tpart[(size_t)n * HID + lane + 64 * i]);
#pragma unroll
        for (int c = 0; c < NC; c++) {
            float a0 = 0.f, a1 = 0.f;
#pragma unroll
            for (int i = 0; i < 4; i++) {
                float hm = fmaxf(tp[i] + vp[c * HID + lane + 64 * i], 0.f);
                a0 += hm * w20[i];
                a1 += hm * w21[i];
            }
#pragma unroll
            for (int off = 32; off >= 1; off >>= 1) {
                a0 += __shfl_xor(a0, off, 64);
                a1 += __shfl_xor(a1, off, 64);
            }
            if (lane == 0) {
                out[(size_t)c * NT + n] = a0 + b0;
                float z = a1 + b1;
                out[(size_t)NC * NT + (size_t)c * NT + n] = 1.f / (1.f + expf(-z));
            }
        }
    }
}

extern "C" void kernel_launch(void* const* d_in, const int* in_sizes, int n_in,
                              void* d_out, int out_size, void* d_ws, size_t ws_size,
                              hipStream_t stream) {
    (void)in_sizes; (void)n_in; (void)out_size;
    const float* x_v    = (const float*)d_in[0];
    const float* x_t    = (const float*)d_in[1];
    const int* ei_vt_s  = (const int*)d_in[2];
    const int* ei_vt_d  = (const int*)d_in[3];
    const int* ei_tv_s  = (const int*)d_in[4];
    const int* ei_tv_d  = (const int*)d_in[5];
    const int* ei_tt_s  = (const int*)d_in[6];
    const int* ei_tt_d  = (const int*)d_in[7];
    const int* current  = (const int*)d_in[8];
    const float* W_in_v = (const float*)d_in[9];
    const float* b_in_v = (const float*)d_in[10];
    const float* W_in_t = (const float*)d_in[11];
    const float* b_in_t = (const float*)d_in[12];
    const float* Wk     = (const float*)d_in[13];
    const float* bk     = (const float*)d_in[14];
    const float* Wq     = (const float*)d_in[15];
    const float* bq     = (const float*)d_in[16];
    const float* Wv     = (const float*)d_in[17];
    const float* bv     = (const float*)d_in[18];
    const float* Wa     = (const float*)d_in[19];
    const float* ba     = (const float*)d_in[20];
    const float* skip   = (const float*)d_in[21];
    const float* a_rel  = (const float*)d_in[22];
    const float* m_rel  = (const float*)d_in[23];
    const float* p_rel  = (const float*)d_in[24];
    const float* Ws1    = (const float*)d_in[25];
    const float* bs1    = (const float*)d_in[26];
    const float* Ws2    = (const float*)d_in[27];
    const float* bs2    = (const float*)d_in[28];

    char* p = (char*)d_ws;
    auto alloc = [&](size_t bytes) -> char* {
        char* r = p;
        p += (bytes + 255) & ~(size_t)255;
        return r;
    };
    u16* hv   = (u16*)alloc((size_t)NV * HID * 2);
    u16* ht   = (u16*)alloc((size_t)NT * HID * 2);
    u16* qb   = (u16*)alloc((size_t)NT * HID * 2);
    u16* qv   = (u16*)alloc((size_t)NV * HID * 2);
    u16* kA   = (u16*)alloc((size_t)NT * HID * 2); // reused as bf16 tpart at the end
    u16* vM   = (u16*)alloc((size_t)NT * HID * 2);
    u16* kA0  = (u16*)alloc((size_t)NV * HID * 2);
    u16* vM0  = (u16*)alloc((size_t)NV * HID * 2);
    u16* agg  = (u16*)alloc((size_t)NT * HID * 2);
    int* rp_vt = (int*)alloc((size_t)(NT + 1) * 4);
    int* rp_tv = (int*)alloc((size_t)(NV + 1) * 4);
    int* rp_tt = (int*)alloc((size_t)(NT + 1) * 4);
    int* es_vt = (int*)alloc((size_t)NE * 4);
    int* es_tv = (int*)alloc((size_t)NE * 4);
    int* es_tt = (int*)alloc((size_t)NE * 4);
    int* cnt3  = (int*)alloc((size_t)3 * NT * 4);
    int* fill3 = (int*)alloc((size_t)3 * NT * 4);
    float* vp  = (float*)alloc((size_t)NC * HID * 4);
    float* bkF = (float*)alloc(HID * 4);
    float* bvF = (float*)alloc(HID * 4);
    u16*  wswK = (u16*)alloc((size_t)HID * HID * 2);
    u16*  wswV = (u16*)alloc((size_t)HID * HID * 2);
    u16*  wswK2 = (u16*)alloc((size_t)HID * HID * 2);
    u16*  wswV2 = (u16*)alloc((size_t)HID * HID * 2);
    float* bkF2 = (float*)alloc(HID * 4);
    float* bvF2 = (float*)alloc(HID * 4);
    u16*  wswA = (u16*)alloc((size_t)9 * HID * HID * 2);
    if ((size_t)(p - (char*)d_ws) > ws_size) return; // clean fail -> zeros signature

    const float scale = 0.17677669529663687f;

    // ---- build 3 CSRs (batched: 5 launches, scans concurrent) ----
    k_zero_i<<<256, 256, 0, stream>>>(cnt3, 3 * NT);
    k_hist3<<<3 * 512, 256, 0, stream>>>(ei_vt_d, ei_tv_d, ei_tt_d, cnt3);
    k_scan3<<<3, 1024, 0, stream>>>(cnt3, rp_vt, rp_tv, rp_tt);
    k_copy3<<<3 * 256, 256, 0, stream>>>(rp_vt, rp_tv, rp_tt, fill3);
    k_scatter3<<<3 * 512, 256, 0, stream>>>(ei_vt_d, ei_vt_s, ei_tv_d, ei_tv_s, ei_tt_d, ei_tt_s,
                                            fill3, es_vt, es_tv, es_tt);

    // ---- swizzle all static weights in one launch ----
    k_swz_multi<<<9 * 256, 256, 0, stream>>>(Wq, Wa, Ws1, wswA);

    k_in_proj<<<(NV + 15) / 16, 256, 0, stream>>>(x_v, W_in_v, b_in_v, hv, NV);
    k_in_proj<<<(NT + 15) / 16, 256, 0, stream>>>(x_t, W_in_t, b_in_t, ht, NT);

    const int GV = (NV + 15) / 16, GT = (NT + 15) / 16;

    for (int l = 0; l < NL; l++) {
        const float* Wk0 = Wk + (size_t)(l * 2 + 0) * HID * HID;
        const float* Wk1 = Wk + (size_t)(l * 2 + 1) * HID * HID;
        const float* bk0 = bk + (l * 2 + 0) * HID, *bk1 = bk + (l * 2 + 1) * HID;
        const float* Wv0 = Wv + (size_t)(l * 2 + 0) * HID * HID;
        const float* Wv1 = Wv + (size_t)(l * 2 + 1) * HID * HID;
        const float* bv0 = bv + (l * 2 + 0) * HID, *bv1 = bv + (l * 2 + 1) * HID;
        const float* bq0 = bq + (l * 2 + 0) * HID, *bq1 = bq + (l * 2 + 1) * HID;
        const u16* WqS0 = wswA + (size_t)(l * 2 + 0) * 65536;
        const u16* WqS1 = wswA + (size_t)(l * 2 + 1) * 65536;
        const u16* WaS0 = wswA + (size_t)(4 + l * 2 + 0) * 65536;
        const u16* WaS1 = wswA + (size_t)(4 + l * 2 + 1) * 65536;
        const float* A0 = a_rel + (size_t)(l * 3 + 0) * NH * DH * DH;
        const float* A1 = a_rel + (size_t)(l * 3 + 1) * NH * DH * DH;
        const float* A2 = a_rel + (size_t)(l * 3 + 2) * NH * DH * DH;
        const float* M0 = m_rel + (size_t)(l * 3 + 0) * NH * DH * DH;
        const float* M1 = m_rel + (size_t)(l * 3 + 1) * NH * DH * DH;
        const float* M2 = m_rel + (size_t)(l * 3 + 2) * NH * DH * DH;
        const float* P0 = p_rel + (size_t)(l * 3 + 0) * NH;
        const float* P1 = p_rel + (size_t)(l * 3 + 1) * NH;
        const float* P2 = p_rel + (size_t)(l * 3 + 2) * NH;

        // A. r0 (v->t) weights; fused q_v + k0 + v0 from OLD hv (one A read)
        k_fuse_w<<<NH, 256, 0, stream>>>(Wk0, bk0, A0, wswK, bkF);
        k_fuse_w<<<NH, 256, 0, stream>>>(Wv0, bv0, M0, wswV, bvF);
        k_mm3<<<GV, 256, 0, stream>>>(hv, WqS0, bq0, qv, wswK, bkF, kA0, wswV, bvF, vM0, NV);

        // B. r1 (t->v) weights; fused q_t + k1 + v1 from OLD ht (one A read)
        k_fuse_w<<<NH, 256, 0, stream>>>(Wk1, bk1, A1, wswK, bkF);
        k_fuse_w<<<NH, 256, 0, stream>>>(Wv1, bv1, M1, wswV, bvF);
        k_mm3<<<GT, 256, 0, stream>>>(ht, WqS1, bq1, qb, wswK, bkF, kA, wswV, bvF, vM, NT);

        // C. aggregate r1 into agg (dst = v)
        k_node_attn<<<(NV + 3) / 4, 256, 0, stream>>>(qv, kA, vM, rp_tv, es_tv, P1, scale, agg, NV);

        // D. update hv (old hv fully consumed)
        k_mm<2, 1><<<GV, 256, 0, stream>>>(agg, WaS0, ba + (l * 2 + 0) * HID, hv, skip + (l * 2 + 0), NV);

        // E. r2 (t->t) projections from OLD ht (kA/vM from r1 dead after C)
        k_fuse_w<<<NH, 256, 0, stream>>>(Wk1, bk1, A2, wswK2, bkF2);
        k_fuse_w<<<NH, 256, 0, stream>>>(Wv1, bv1, M2, wswV2, bvF2);
        k_mm2<<<GT, 256, 0, stream>>>(ht, wswK2, bkF2, kA, wswV2, bvF2, vM, NT);

        // F. combined dst=t aggregation: r0 (kA0/vM0) + r2 (kA/vM), fused interleaved loop
        k_node_attn2<<<(NT + 3) / 4, 256, 0, stream>>>(qb, kA0, vM0, rp_vt, es_vt, P0,
                                                       kA, vM, rp_tt, es_tt, P2, scale, agg, NT);

        // G. update ht
        k_mm<2, 1><<<GT, 256, 0, stream>>>(agg, WaS1, ba + (l * 2 + 1) * HID, ht, skip + (l * 2 + 1), NT);
    }

    k_vpart<<<1, 256, 0, stream>>>(hv, current, Ws1, bs1, vp);
    u16* tpart = kA; // bf16 tpart
    k_mm<3, 0><<<GT, 256, 0, stream>>>(ht, wswA + (size_t)8 * 65536, nullptr, (void*)tpart, nullptr, NT);
    k_final<<<2048, 256, 0, stream>>>(tpart, vp, Ws2, bs2, (float*)d_out);
}

// Round 20
// 989.607 us; speedup vs baseline: 1.1100x; 1.1100x over previous
//
#include <hip/hip_runtime.h>
#include <hip/hip_bf16.h>
#include <math.h>

#define HID 256
#define NH 8
#define DH 32
#define NL 2
#define NV 20000
#define NT 50000
#define NE 100000
#define NC 8
#define FIN 64

typedef unsigned short u16;
typedef unsigned int u32;
typedef short s16x8 __attribute__((ext_vector_type(8)));
typedef float f32x4 __attribute__((ext_vector_type(4)));

__device__ __forceinline__ float bf2f(u16 u) { return __uint_as_float(((u32)u) << 16); }
__device__ __forceinline__ u16 f2bf(float f) {
    u32 x = __float_as_uint(f);
    u32 r = ((x >> 16) & 1u) + 0x7fffu;
    return (u16)((x + r) >> 16);
}
__device__ __forceinline__ void up2(u32 u, float& a, float& b) {
    a = __uint_as_float(u << 16);
    b = __uint_as_float(u & 0xffff0000u);
}
__device__ __forceinline__ s16x8 gelu8(s16x8 a) {
    s16x8 r;
#pragma unroll
    for (int i = 0; i < 8; i++) {
        float v = bf2f((u16)a[i]);
        v = 0.5f * v * (1.f + erff(v * 0.70710678118654752f));
        r[i] = (short)f2bf(v);
    }
    return r;
}

// ---------------- zero fill ----------------
__global__ void k_zero_i(int* __restrict__ p, int n) {
    for (int i = blockIdx.x * 256 + threadIdx.x; i < n; i += gridDim.x * 256) p[i] = 0;
}

// ---------------- batched histogram of 3 dst arrays ----------------
__global__ void k_hist3(const int* __restrict__ d0, const int* __restrict__ d1, const int* __restrict__ d2,
                        int* __restrict__ cnt3) {
    int r = blockIdx.x >> 9;        // 0..2
    int b = blockIdx.x & 511;
    const int* dst = (r == 0) ? d0 : (r == 1) ? d1 : d2;
    int* cnt = cnt3 + (size_t)r * NT;
    for (int e = b * 256 + threadIdx.x; e < NE; e += 512 * 256)
        atomicAdd(&cnt[dst[e]], 1);
}

// ---------------- batched serial scans ----------------
__global__ __launch_bounds__(1024) void k_scan3(const int* __restrict__ cnt3,
                                                int* __restrict__ rp0, int* __restrict__ rp1, int* __restrict__ rp2) {
    int r = blockIdx.x;
    const int* cnt = cnt3 + (size_t)r * NT;
    int* rp = (r == 0) ? rp0 : (r == 1) ? rp1 : rp2;
    int n = (r == 1) ? NV : NT;
    __shared__ int wsum[16];
    __shared__ int carry_s;
    int t = threadIdx.x, lane = t & 63, wv = t >> 6;
    if (t == 0) { carry_s = 0; rp[0] = 0; }
    __syncthreads();
    for (int base = 0; base < n; base += 1024) {
        int v = (base + t < n) ? cnt[base + t] : 0;
        int x = v;
#pragma unroll
        for (int off = 1; off < 64; off <<= 1) {
            int y = __shfl_up(x, off, 64);
            if (lane >= off) x += y;
        }
        if (lane == 63) wsum[wv] = x;
        __syncthreads();
        if (wv == 0 && lane < 16) {
            int s = wsum[lane];
#pragma unroll
            for (int off = 1; off < 16; off <<= 1) {
                int y = __shfl_up(s, off, 64);
                if (lane >= off) s += y;
            }
            wsum[lane] = s;
        }
        __syncthreads();
        int prefix = carry_s + (wv > 0 ? wsum[wv - 1] : 0);
        if (base + t < n) rp[base + t + 1] = prefix + x;
        __syncthreads();
        if (t == 0) carry_s += wsum[15];
        __syncthreads();
    }
}

// ---------------- batched fill copy ----------------
__global__ void k_copy3(const int* __restrict__ rp0, const int* __restrict__ rp1, const int* __restrict__ rp2,
                        int* __restrict__ fill3) {
    int r = blockIdx.x >> 8;
    int b = blockIdx.x & 255;
    const int* rp = (r == 0) ? rp0 : (r == 1) ? rp1 : rp2;
    int n = (r == 1) ? NV : NT;
    int* fill = fill3 + (size_t)r * NT;
    for (int i = b * 256 + threadIdx.x; i < n; i += 256 * 256) fill[i] = rp[i];
}

// ---------------- batched scatter ----------------
__global__ void k_scatter3(const int* __restrict__ d0, const int* __restrict__ s0,
                           const int* __restrict__ d1, const int* __restrict__ s1,
                           const int* __restrict__ d2, const int* __restrict__ s2,
                           int* __restrict__ fill3,
                           int* __restrict__ es0, int* __restrict__ es1, int* __restrict__ es2) {
    int r = blockIdx.x >> 9;
    int b = blockIdx.x & 511;
    const int* dst = (r == 0) ? d0 : (r == 1) ? d1 : d2;
    const int* src = (r == 0) ? s0 : (r == 1) ? s1 : s2;
    int* fill = fill3 + (size_t)r * NT;
    int* es = (r == 0) ? es0 : (r == 1) ? es1 : es2;
    for (int e = b * 256 + threadIdx.x; e < NE; e += 512 * 256) {
        int d = dst[e];
        int p = atomicAdd(&fill[d], 1);
        es[p] = src[e];
    }
}

// ---------------- input projection ----------------
__global__ __launch_bounds__(256) void k_in_proj(const float* __restrict__ X, const float* __restrict__ W,
                          const float* __restrict__ b, u16* __restrict__ Y, int N) {
    const int NPB = 16;
    __shared__ float xs[NPB][FIN];
    int n0 = blockIdx.x * NPB;
    int t = threadIdx.x;
    for (int idx = t; idx < NPB * FIN; idx += 256) {
        int i = idx >> 6, c = idx & 63;
        int n = n0 + i;
        xs[i][c] = (n < N) ? X[(size_t)n * FIN + c] : 0.f;
    }
    __syncthreads();
    float acc[NPB];
#pragma unroll
    for (int i = 0; i < NPB; i++) acc[i] = 0.f;
    for (int c = 0; c < FIN; c++) {
        float w = W[c * HID + t];
#pragma unroll
        for (int i = 0; i < NPB; i++) acc[i] += xs[i][c] * w;
    }
    float bb = b[t];
    for (int i = 0; i < NPB; i++) {
        int n = n0 + i;
        if (n < N) Y[(size_t)n * HID + t] = f2bf(fmaxf(acc[i] + bb, 0.f));
    }
}

// swizzle index for MFMA B fragment
__device__ __forceinline__ int swz_idx(int k, int n) {
    int ks = k >> 5, r = k & 31;
    int j = r & 7;
    int l = ((r >> 3) << 4) | (n & 15);
    int nt = n >> 4;
    return ((ks * 16 + nt) * 64 + l) * 8 + j;
}

// ---------------- dual fuse: k and v weight pairs in one launch (16 blocks) ----------------
__global__ __launch_bounds__(256) void k_fuse_w2(
        const float* __restrict__ Wk_, const float* __restrict__ bk_, const float* __restrict__ Rk,
        u16* __restrict__ WswK, float* __restrict__ bkO,
        const float* __restrict__ Wv_, const float* __restrict__ bv_, const float* __restrict__ Rv,
        u16* __restrict__ WswV, float* __restrict__ bvO) {
    int h = blockIdx.x & 7;
    int which = blockIdx.x >> 3;
    const float* W = which ? Wv_ : Wk_;
    const float* b = which ? bv_ : bk_;
    const float* R = which ? Rv : Rk;
    u16* Wsw = which ? WswV : WswK;
    float* bout = which ? bvO : bkO;
    __shared__ float sR[DH * DH];
    int t = threadIdx.x;
    for (int idx = t; idx < DH * DH; idx += 256) sR[idx] = R[h * DH * DH + idx];
    __syncthreads();
    int f = t & 31, c0 = t >> 5;
    for (int c = c0; c < HID; c += 8) {
        float acc = 0.f;
#pragma unroll
        for (int d = 0; d < DH; d++) acc += W[c * HID + h * DH + d] * sR[d * DH + f];
        Wsw[swz_idx(c, h * DH + f)] = f2bf(acc);
    }
    if (t < DH) {
        float acc = 0.f;
#pragma unroll
        for (int d = 0; d < DH; d++) acc += b[h * DH + d] * sR[d * DH + t];
        bout[h * DH + t] = acc;
    }
}

// ---------------- batched swizzle of 9 static weights ----------------
__global__ __launch_bounds__(256) void k_swz_multi(const float* __restrict__ Wq, const float* __restrict__ Wa,
                                                   const float* __restrict__ Ws1, u16* __restrict__ out) {
    int slot = blockIdx.x >> 8;
    int idx = ((blockIdx.x & 255) << 8) | threadIdx.x;
    const float* src = (slot < 4) ? (Wq + (size_t)slot * 65536)
                     : (slot < 8) ? (Wa + (size_t)(slot - 4) * 65536)
                                  : Ws1;
    int j = idx & 7, l = (idx >> 3) & 63, nt = (idx >> 9) & 15, ks = idx >> 13;
    int k = ks * 32 + (l >> 4) * 8 + j;
    int n = nt * 16 + (l & 15);
    out[(size_t)slot * 65536 + idx] = f2bf(src[k * HID + n]);
}

// ---------------- MFMA GEMM, slim-wave ----------------
// MODE 0: bf16+bias. MODE 1: f32, no bias. MODE 2: skip-mix bf16. MODE 3: bf16, no bias.
template <int MODE, int GELU>
__global__ __launch_bounds__(256) void k_mm(const u16* __restrict__ X, const u16* __restrict__ Wsw,
                                            const float* __restrict__ bias, void* __restrict__ Y,
                                            const float* __restrict__ skip_, int N) {
    int tid = threadIdx.x;
    int w = tid >> 6, lane = tid & 63;
    int r0 = blockIdx.x * 16;
    int rA = r0 + (lane & 15);
    int koffg = lane >> 4;
    s16x8 a[8];
    if (rA < N) {
        const s16x8* ap = (const s16x8*)(X + (size_t)rA * HID) + koffg;
#pragma unroll
        for (int ks = 0; ks < 8; ks++) a[ks] = ap[ks * 4];
    } else {
#pragma unroll
        for (int ks = 0; ks < 8; ks++) a[ks] = (s16x8){0, 0, 0, 0, 0, 0, 0, 0};
    }
    if (GELU) {
#pragma unroll
        for (int ks = 0; ks < 8; ks++) a[ks] = gelu8(a[ks]);
    }
    f32x4 acc[4];
#pragma unroll
    for (int nt = 0; nt < 4; nt++) acc[nt] = (f32x4){0.f, 0.f, 0.f, 0.f};
    const s16x8* wp = (const s16x8*)Wsw;
#pragma unroll
    for (int ks = 0; ks < 8; ks++) {
        const s16x8* wq = wp + (size_t)ks * 16 * 64 + lane;
#pragma unroll
        for (int nt = 0; nt < 4; nt++) {
            s16x8 b = wq[(w * 4 + nt) * 64];
            acc[nt] = __builtin_amdgcn_mfma_f32_16x16x32_bf16(a[ks], b, acc[nt], 0, 0, 0);
        }
    }
    int colb = lane & 15;
    int rowb = r0 + koffg * 4;
    float beta = 0.f, ombeta = 0.f;
    if (MODE == 2) { beta = 1.f / (1.f + expf(-skip_[0])); ombeta = 1.f - beta; }
#pragma unroll
    for (int nt = 0; nt < 4; nt++) {
        int col = w * 64 + nt * 16 + colb;
        float bb = (MODE == 1 || MODE == 3) ? 0.f : bias[col];
#pragma unroll
        for (int j = 0; j < 4; j++) {
            int row = rowb + j;
            if (row < N) {
                float v = acc[nt][j] + bb;
                if (MODE == 0 || MODE == 3) {
                    ((u16*)Y)[(size_t)row * HID + col] = f2bf(v);
                } else if (MODE == 1) {
                    ((float*)Y)[(size_t)row * HID + col] = v;
                } else {
                    u16* hp = (u16*)Y + (size_t)row * HID + col;
                    *hp = f2bf(beta * v + ombeta * bf2f(*hp));
                }
            }
        }
    }
}

// ---------------- fused ht-update + tpart GEMM (layer 1 step G) ----------------
// pass1: o = beta*(gelu(agg)@Wa + ba) + (1-beta)*ht_old  -> LDS only (ht dead after)
// pass2: tpart = LDS_tile @ Ws1 (bf16 out, no bias)
__global__ __launch_bounds__(256) void k_mm_gt(const u16* __restrict__ agg, const u16* __restrict__ WaSw,
                                               const float* __restrict__ ba_, const float* __restrict__ skip_,
                                               const u16* __restrict__ ht_old, const u16* __restrict__ Ws1Sw,
                                               u16* __restrict__ tpart, int N) {
    __shared__ u16 sH[16][264]; // padded: 528B rows -> 2-way bank aliasing (free), 16B aligned
    int tid = threadIdx.x;
    int w = tid >> 6, lane = tid & 63;
    int r0 = blockIdx.x * 16;
    int rA = r0 + (lane & 15);
    int koffg = lane >> 4;
    // pass 1
    s16x8 a[8];
    {
        const s16x8* ap = (const s16x8*)(agg + (size_t)rA * HID) + koffg;
#pragma unroll
        for (int ks = 0; ks < 8; ks++) a[ks] = gelu8(ap[ks * 4]);
    }
    f32x4 acc[4];
#pragma unroll
    for (int nt = 0; nt < 4; nt++) acc[nt] = (f32x4){0.f, 0.f, 0.f, 0.f};
    const s16x8* wp = (const s16x8*)WaSw;
#pragma unroll
    for (int ks = 0; ks < 8; ks++) {
        const s16x8* wq = wp + (size_t)ks * 16 * 64 + lane;
#pragma unroll
        for (int nt = 0; nt < 4; nt++)
            acc[nt] = __builtin_amdgcn_mfma_f32_16x16x32_bf16(a[ks], wq[(w * 4 + nt) * 64], acc[nt], 0, 0, 0);
    }
    float beta = 1.f / (1.f + expf(-skip_[0])), ombeta = 1.f - beta;
    int colb = lane & 15;
    int rowl = koffg * 4;
#pragma unroll
    for (int nt = 0; nt < 4; nt++) {
        int col = w * 64 + nt * 16 + colb;
        float bb = ba_[col];
#pragma unroll
        for (int j = 0; j < 4; j++) {
            int row = r0 + rowl + j;
            float v = acc[nt][j] + bb;
            float o = beta * v + ombeta * bf2f(ht_old[(size_t)row * HID + col]);
            sH[rowl + j][col] = f2bf(o);
        }
    }
    __syncthreads();
    // pass 2: A from LDS (same fragment mapping: row = lane&15, k-slice = koffg*8)
    s16x8 a2[8];
#pragma unroll
    for (int ks = 0; ks < 8; ks++)
        a2[ks] = *(const s16x8*)&sH[lane & 15][ks * 32 + koffg * 8];
#pragma unroll
    for (int nt = 0; nt < 4; nt++) acc[nt] = (f32x4){0.f, 0.f, 0.f, 0.f};
    const s16x8* wp2 = (const s16x8*)Ws1Sw;
#pragma unroll
    for (int ks = 0; ks < 8; ks++) {
        const s16x8* wq = wp2 + (size_t)ks * 16 * 64 + lane;
#pragma unroll
        for (int nt = 0; nt < 4; nt++)
            acc[nt] = __builtin_amdgcn_mfma_f32_16x16x32_bf16(a2[ks], wq[(w * 4 + nt) * 64], acc[nt], 0, 0, 0);
    }
#pragma unroll
    for (int nt = 0; nt < 4; nt++) {
        int col = w * 64 + nt * 16 + colb;
#pragma unroll
        for (int j = 0; j < 4; j++) {
            int row = r0 + rowl + j;
            if (row < N) tpart[(size_t)row * HID + col] = f2bf(acc[nt][j]);
        }
    }
}

// ---------------- dual-B slim-wave MFMA GEMM (A loaded once) ----------------
__global__ __launch_bounds__(256) void k_mm2(const u16* __restrict__ X,
                                             const u16* __restrict__ W1, const float* __restrict__ b1, u16* __restrict__ Y1,
                                             const u16* __restrict__ W2, const float* __restrict__ b2, u16* __restrict__ Y2,
                                             int N) {
    int tid = threadIdx.x;
    int w = tid >> 6, lane = tid & 63;
    int r0 = blockIdx.x * 16;
    int rA = r0 + (lane & 15);
    int koffg = lane >> 4;
    s16x8 a[8];
    if (rA < N) {
        const s16x8* ap = (const s16x8*)(X + (size_t)rA * HID) + koffg;
#pragma unroll
        for (int ks = 0; ks < 8; ks++) a[ks] = ap[ks * 4];
    } else {
#pragma unroll
        for (int ks = 0; ks < 8; ks++) a[ks] = (s16x8){0, 0, 0, 0, 0, 0, 0, 0};
    }
    int colb = lane & 15;
    int rowb = r0 + koffg * 4;
#pragma unroll
    for (int pass = 0; pass < 2; pass++) {
        const u16* Wsw = pass ? W2 : W1;
        const float* bias = pass ? b2 : b1;
        u16* Y = pass ? Y2 : Y1;
        f32x4 acc[4];
#pragma unroll
        for (int nt = 0; nt < 4; nt++) acc[nt] = (f32x4){0.f, 0.f, 0.f, 0.f};
        const s16x8* wp = (const s16x8*)Wsw;
#pragma unroll
        for (int ks = 0; ks < 8; ks++) {
            const s16x8* wq = wp + (size_t)ks * 16 * 64 + lane;
#pragma unroll
            for (int nt = 0; nt < 4; nt++) {
                s16x8 b = wq[(w * 4 + nt) * 64];
                acc[nt] = __builtin_amdgcn_mfma_f32_16x16x32_bf16(a[ks], b, acc[nt], 0, 0, 0);
            }
        }
#pragma unroll
        for (int nt = 0; nt < 4; nt++) {
            int col = w * 64 + nt * 16 + colb;
            float bb = bias[col];
#pragma unroll
            for (int j = 0; j < 4; j++) {
                int row = rowb + j;
                if (row < N) Y[(size_t)row * HID + col] = f2bf(acc[nt][j] + bb);
            }
        }
    }
}

// ---------------- triple-B slim-wave MFMA GEMM: q + k + v from one A read ----------------
__global__ __launch_bounds__(256) void k_mm3(const u16* __restrict__ X,
                                             const u16* __restrict__ W0, const float* __restrict__ b0, u16* __restrict__ Y0,
                                             const u16* __restrict__ W1, const float* __restrict__ b1, u16* __restrict__ Y1,
                                             const u16* __restrict__ W2, const float* __restrict__ b2, u16* __restrict__ Y2,
                                             int N) {
    int tid = threadIdx.x;
    int w = tid >> 6, lane = tid & 63;
    int r0 = blockIdx.x * 16;
    int rA = r0 + (lane & 15);
    int koffg = lane >> 4;
    s16x8 a[8];
    if (rA < N) {
        const s16x8* ap = (const s16x8*)(X + (size_t)rA * HID) + koffg;
#pragma unroll
        for (int ks = 0; ks < 8; ks++) a[ks] = ap[ks * 4];
    } else {
#pragma unroll
        for (int ks = 0; ks < 8; ks++) a[ks] = (s16x8){0, 0, 0, 0, 0, 0, 0, 0};
    }
    int colb = lane & 15;
    int rowb = r0 + koffg * 4;
#pragma unroll
    for (int pass = 0; pass < 3; pass++) {
        const u16* Wsw = (pass == 0) ? W0 : (pass == 1) ? W1 : W2;
        const float* bias = (pass == 0) ? b0 : (pass == 1) ? b1 : b2;
        u16* Y = (pass == 0) ? Y0 : (pass == 1) ? Y1 : Y2;
        f32x4 acc[4];
#pragma unroll
        for (int nt = 0; nt < 4; nt++) acc[nt] = (f32x4){0.f, 0.f, 0.f, 0.f};
        const s16x8* wp = (const s16x8*)Wsw;
#pragma unroll
        for (int ks = 0; ks < 8; ks++) {
            const s16x8* wq = wp + (size_t)ks * 16 * 64 + lane;
#pragma unroll
            for (int nt = 0; nt < 4; nt++) {
                s16x8 b = wq[(w * 4 + nt) * 64];
                acc[nt] = __builtin_amdgcn_mfma_f32_16x16x32_bf16(a[ks], b, acc[nt], 0, 0, 0);
            }
        }
#pragma unroll
        for (int nt = 0; nt < 4; nt++) {
            int col = w * 64 + nt * 16 + colb;
            float bb = bias[col];
#pragma unroll
            for (int j = 0; j < 4; j++) {
                int row = rowb + j;
                if (row < N) Y[(size_t)row * HID + col] = f2bf(acc[nt][j] + bb);
            }
        }
    }
}

// ---------------- online-softmax over one CSR, 2-deep prefetch ----------------
__device__ __forceinline__ void attn_pass(const u16* __restrict__ kA, const u16* __restrict__ vM,
                                          const int* __restrict__ es, int jb, int je,
                                          float q0, float q1, float q2, float q3, float ph, int lane4,
                                          float& o0, float& o1, float& o2, float& o3) {
    float m = -INFINITY, ss = 0.f, a0 = 0.f, a1 = 0.f, a2 = 0.f, a3 = 0.f;
    uint2 ku0 = {0, 0}, vu0 = {0, 0}, ku1 = {0, 0}, vu1 = {0, 0};
    if (jb < je) {
        int s = es[jb];
        ku0 = *(const uint2*)(kA + (size_t)s * HID + lane4);
        vu0 = *(const uint2*)(vM + (size_t)s * HID + lane4);
    }
    if (jb + 1 < je) {
        int s = es[jb + 1];
        ku1 = *(const uint2*)(kA + (size_t)s * HID + lane4);
        vu1 = *(const uint2*)(vM + (size_t)s * HID + lane4);
    }
    for (int j = jb; j < je; j++) {
        uint2 ku = ku0, vu = vu0;
        ku0 = ku1; vu0 = vu1;
        if (j + 2 < je) {
            int s = es[j + 2];
            ku1 = *(const uint2*)(kA + (size_t)s * HID + lane4);
            vu1 = *(const uint2*)(vM + (size_t)s * HID + lane4);
        }
        float k0, k1, k2, k3; up2(ku.x, k0, k1); up2(ku.y, k2, k3);
        float part = q0 * k0 + q1 * k1 + q2 * k2 + q3 * k3;
        part += __shfl_xor(part, 1, 64);
        part += __shfl_xor(part, 2, 64);
        part += __shfl_xor(part, 4, 64);
        float logit = part * ph;
        float nm = fmaxf(m, logit);
        float corr = expf(m - nm);
        float ee = expf(logit - nm);
        float v0, v1, v2, v3; up2(vu.x, v0, v1); up2(vu.y, v2, v3);
        ss = ss * corr + ee;
        a0 = a0 * corr + ee * v0; a1 = a1 * corr + ee * v1;
        a2 = a2 * corr + ee * v2; a3 = a3 * corr + ee * v3;
        m = nm;
    }
    float inv = 1.f / (ss + 1e-16f);
    o0 += a0 * inv; o1 += a1 * inv; o2 += a2 * inv; o3 += a3 * inv;
}

// ---------------- single-relation node attention ----------------
__global__ __launch_bounds__(256) void k_node_attn(
        const u16* __restrict__ q, const u16* __restrict__ kA, const u16* __restrict__ vM,
        const int* __restrict__ rp, const int* __restrict__ es,
        const float* __restrict__ P, float scale,
        u16* __restrict__ agg, int Nd) {
    int node = blockIdx.x * 4 + (threadIdx.x >> 6);
    if (node >= Nd) return;
    int lane = threadIdx.x & 63;
    float ph = P[lane >> 3] * scale;
    uint2 qu = *(const uint2*)(q + (size_t)node * HID + lane * 4);
    float q0, q1, q2, q3; up2(qu.x, q0, q1); up2(qu.y, q2, q3);
    float o0 = 0.f, o1 = 0.f, o2 = 0.f, o3 = 0.f;
    attn_pass(kA, vM, es, rp[node], rp[node + 1], q0, q1, q2, q3, ph, lane * 4, o0, o1, o2, o3);
    u16* ap = agg + (size_t)node * HID + lane * 4;
    ap[0] = f2bf(o0); ap[1] = f2bf(o1); ap[2] = f2bf(o2); ap[3] = f2bf(o3);
}

// ---------------- dual-relation node attention (dst=t: r0 + r2, f32 sum) ----------------
__global__ __launch_bounds__(256) void k_node_attn2(
        const u16* __restrict__ q,
        const u16* __restrict__ kA0, const u16* __restrict__ vM0,
        const int* __restrict__ rp0, const int* __restrict__ es0, const float* __restrict__ P0,
        const u16* __restrict__ kA1, const u16* __restrict__ vM1,
        const int* __restrict__ rp1, const int* __restrict__ es1, const float* __restrict__ P1,
        float scale, u16* __restrict__ agg, int Nd) {
    int node = blockIdx.x * 4 + (threadIdx.x >> 6);
    if (node >= Nd) return;
    int lane = threadIdx.x & 63;
    int h = lane >> 3;
    int lane4 = lane * 4;
    float ph0 = P0[h] * scale, ph1 = P1[h] * scale;
    uint2 qu = *(const uint2*)(q + (size_t)node * HID + lane4);
    float q0, q1, q2, q3; up2(qu.x, q0, q1); up2(qu.y, q2, q3);
    float o0 = 0.f, o1 = 0.f, o2 = 0.f, o3 = 0.f;
    attn_pass(kA0, vM0, es0, rp0[node], rp0[node + 1], q0, q1, q2, q3, ph0, lane4, o0, o1, o2, o3);
    attn_pass(kA1, vM1, es1, rp1[node], rp1[node + 1], q0, q1, q2, q3, ph1, lane4, o0, o1, o2, o3);
    u16* ap = agg + (size_t)node * HID + lane4;
    ap[0] = f2bf(o0); ap[1] = f2bf(o1); ap[2] = f2bf(o2); ap[3] = f2bf(o3);
}

// ---------------- vpart ----------------
__global__ void k_vpart(const u16* __restrict__ hv, const int* __restrict__ current,
                        const float* __restrict__ Ws1, const float* __restrict__ bs1,
                        float* __restrict__ vpart) {
    __shared__ float row[HID];
    int t = threadIdx.x;
    for (int c = 0; c < NC; c++) {
        int n = current[c * 2];
        row[t] = bf2f(hv[(size_t)n * HID + t]);
        __syncthreads();
        float acc = 0.f;
        for (int i = 0; i < HID; i++) acc += row[i] * Ws1[(size_t)(HID + i) * HID + t];
        vpart[c * HID + t] = acc + bs1[t];
        __syncthreads();
    }
}

// ---------------- final: tpart bf16 ----------------
__global__ __launch_bounds__(256) void k_final(const u16* __restrict__ tpart, const float* __restrict__ vpart,
                        const float* __restrict__ Ws2, const float* __restrict__ bs2,
                        float* __restrict__ out) {
    __shared__ float vp[NC * HID];
    int t = threadIdx.x;
    for (int idx = t; idx < NC * HID; idx += 256) vp[idx] = vpart[idx];
    __syncthreads();
    int lane = t & 63, w = t >> 6;
    float w20[4], w21[4];
#pragma unroll
    for (int i = 0; i < 4; i++) {
        w20[i] = Ws2[(lane + 64 * i) * 2 + 0];
        w21[i] = Ws2[(lane + 64 * i) * 2 + 1];
    }
    float b0 = bs2[0], b1 = bs2[1];
    for (int n = blockIdx.x * 4 + w; n < NT; n += gridDim.x * 4) {
        float tp[4];
#pragma unroll
        for (int i = 0; i < 4; i++) tp[i] = bf2f(tpart[(size_t)n * HID + lane + 64 * i]);
#pragma unroll
        for (int c = 0; c < NC; c++) {
            float a0 = 0.f, a1 = 0.f;
#pragma unroll
            for (int i = 0; i < 4; i++) {
                float hm = fmaxf(tp[i] + vp[c * HID + lane + 64 * i], 0.f);
                a0 += hm * w20[i];
                a1 += hm * w21[i];
            }
#pragma unroll
            for (int off = 32; off >= 1; off >>= 1) {
                a0 += __shfl_xor(a0, off, 64);
                a1 += __shfl_xor(a1, off, 64);
            }
            if (lane == 0) {
                out[(size_t)c * NT + n] = a0 + b0;
                float z = a1 + b1;
                out[(size_t)NC * NT + (size_t)c * NT + n] = 1.f / (1.f + expf(-z));
            }
        }
    }
}

extern "C" void kernel_launch(void* const* d_in, const int* in_sizes, int n_in,
                              void* d_out, int out_size, void* d_ws, size_t ws_size,
                              hipStream_t stream) {
    (void)in_sizes; (void)n_in; (void)out_size;
    const float* x_v    = (const float*)d_in[0];
    const float* x_t    = (const float*)d_in[1];
    const int* ei_vt_s  = (const int*)d_in[2];
    const int* ei_vt_d  = (const int*)d_in[3];
    const int* ei_tv_s  = (const int*)d_in[4];
    const int* ei_tv_d  = (const int*)d_in[5];
    const int* ei_tt_s  = (const int*)d_in[6];
    const int* ei_tt_d  = (const int*)d_in[7];
    const int* current  = (const int*)d_in[8];
    const float* W_in_v = (const float*)d_in[9];
    const float* b_in_v = (const float*)d_in[10];
    const float* W_in_t = (const float*)d_in[11];
    const float* b_in_t = (const float*)d_in[12];
    const float* Wk     = (const float*)d_in[13];
    const float* bk     = (const float*)d_in[14];
    const float* Wq     = (const float*)d_in[15];
    const float* bq     = (const float*)d_in[16];
    const float* Wv     = (const float*)d_in[17];
    const float* bv     = (const float*)d_in[18];
    const float* Wa     = (const float*)d_in[19];
    const float* ba     = (const float*)d_in[20];
    const float* skip   = (const float*)d_in[21];
    const float* a_rel  = (const float*)d_in[22];
    const float* m_rel  = (const float*)d_in[23];
    const float* p_rel  = (const float*)d_in[24];
    const float* Ws1    = (const float*)d_in[25];
    const float* bs1    = (const float*)d_in[26];
    const float* Ws2    = (const float*)d_in[27];
    const float* bs2    = (const float*)d_in[28];

    char* p = (char*)d_ws;
    auto alloc = [&](size_t bytes) -> char* {
        char* r = p;
        p += (bytes + 255) & ~(size_t)255;
        return r;
    };
    u16* hv   = (u16*)alloc((size_t)NV * HID * 2);
    u16* ht   = (u16*)alloc((size_t)NT * HID * 2);
    u16* qb   = (u16*)alloc((size_t)NT * HID * 2);
    u16* qv   = (u16*)alloc((size_t)NV * HID * 2);
    u16* kA   = (u16*)alloc((size_t)NT * HID * 2); // reused as bf16 tpart by k_mm_gt (after F)
    u16* vM   = (u16*)alloc((size_t)NT * HID * 2);
    u16* kA0  = (u16*)alloc((size_t)NV * HID * 2);
    u16* vM0  = (u16*)alloc((size_t)NV * HID * 2);
    u16* agg  = (u16*)alloc((size_t)NT * HID * 2);
    int* rp_vt = (int*)alloc((size_t)(NT + 1) * 4);
    int* rp_tv = (int*)alloc((size_t)(NV + 1) * 4);
    int* rp_tt = (int*)alloc((size_t)(NT + 1) * 4);
    int* es_vt = (int*)alloc((size_t)NE * 4);
    int* es_tv = (int*)alloc((size_t)NE * 4);
    int* es_tt = (int*)alloc((size_t)NE * 4);
    int* cnt3  = (int*)alloc((size_t)3 * NT * 4);
    int* fill3 = (int*)alloc((size_t)3 * NT * 4);
    float* vp  = (float*)alloc((size_t)NC * HID * 4);
    float* bkF = (float*)alloc(HID * 4);
    float* bvF = (float*)alloc(HID * 4);
    u16*  wswK = (u16*)alloc((size_t)HID * HID * 2);
    u16*  wswV = (u16*)alloc((size_t)HID * HID * 2);
    u16*  wswK2 = (u16*)alloc((size_t)HID * HID * 2);
    u16*  wswV2 = (u16*)alloc((size_t)HID * HID * 2);
    float* bkF2 = (float*)alloc(HID * 4);
    float* bvF2 = (float*)alloc(HID * 4);
    u16*  wswA = (u16*)alloc((size_t)9 * HID * HID * 2);
    if ((size_t)(p - (char*)d_ws) > ws_size) return; // clean fail -> zeros signature

    const float scale = 0.17677669529663687f;

    // ---- build 3 CSRs (batched) ----
    k_zero_i<<<256, 256, 0, stream>>>(cnt3, 3 * NT);
    k_hist3<<<3 * 512, 256, 0, stream>>>(ei_vt_d, ei_tv_d, ei_tt_d, cnt3);
    k_scan3<<<3, 1024, 0, stream>>>(cnt3, rp_vt, rp_tv, rp_tt);
    k_copy3<<<3 * 256, 256, 0, stream>>>(rp_vt, rp_tv, rp_tt, fill3);
    k_scatter3<<<3 * 512, 256, 0, stream>>>(ei_vt_d, ei_vt_s, ei_tv_d, ei_tv_s, ei_tt_d, ei_tt_s,
                                            fill3, es_vt, es_tv, es_tt);

    // ---- swizzle all static weights in one launch ----
    k_swz_multi<<<9 * 256, 256, 0, stream>>>(Wq, Wa, Ws1, wswA);

    k_in_proj<<<(NV + 15) / 16, 256, 0, stream>>>(x_v, W_in_v, b_in_v, hv, NV);
    k_in_proj<<<(NT + 15) / 16, 256, 0, stream>>>(x_t, W_in_t, b_in_t, ht, NT);

    const int GV = (NV + 15) / 16, GT = (NT + 15) / 16;

    for (int l = 0; l < NL; l++) {
        const float* Wk0 = Wk + (size_t)(l * 2 + 0) * HID * HID;
        const float* Wk1 = Wk + (size_t)(l * 2 + 1) * HID * HID;
        const float* bk0 = bk + (l * 2 + 0) * HID, *bk1 = bk + (l * 2 + 1) * HID;
        const float* Wv0 = Wv + (size_t)(l * 2 + 0) * HID * HID;
        const float* Wv1 = Wv + (size_t)(l * 2 + 1) * HID * HID;
        const float* bv0 = bv + (l * 2 + 0) * HID, *bv1 = bv + (l * 2 + 1) * HID;
        const float* bq0 = bq + (l * 2 + 0) * HID, *bq1 = bq + (l * 2 + 1) * HID;
        const u16* WqS0 = wswA + (size_t)(l * 2 + 0) * 65536;
        const u16* WqS1 = wswA + (size_t)(l * 2 + 1) * 65536;
        const u16* WaS0 = wswA + (size_t)(4 + l * 2 + 0) * 65536;
        const u16* WaS1 = wswA + (size_t)(4 + l * 2 + 1) * 65536;
        const float* A0 = a_rel + (size_t)(l * 3 + 0) * NH * DH * DH;
        const float* A1 = a_rel + (size_t)(l * 3 + 1) * NH * DH * DH;
        const float* A2 = a_rel + (size_t)(l * 3 + 2) * NH * DH * DH;
        const float* M0 = m_rel + (size_t)(l * 3 + 0) * NH * DH * DH;
        const float* M1 = m_rel + (size_t)(l * 3 + 1) * NH * DH * DH;
        const float* M2 = m_rel + (size_t)(l * 3 + 2) * NH * DH * DH;
        const float* P0 = p_rel + (size_t)(l * 3 + 0) * NH;
        const float* P1 = p_rel + (size_t)(l * 3 + 1) * NH;
        const float* P2 = p_rel + (size_t)(l * 3 + 2) * NH;

        // A. r0 (v->t) weights (k+v one launch); fused q_v + k0 + v0 from OLD hv
        k_fuse_w2<<<2 * NH, 256, 0, stream>>>(Wk0, bk0, A0, wswK, bkF, Wv0, bv0, M0, wswV, bvF);
        k_mm3<<<GV, 256, 0, stream>>>(hv, WqS0, bq0, qv, wswK, bkF, kA0, wswV, bvF, vM0, NV);

        // B. r1 (t->v) weights; fused q_t + k1 + v1 from OLD ht
        k_fuse_w2<<<2 * NH, 256, 0, stream>>>(Wk1, bk1, A1, wswK, bkF, Wv1, bv1, M1, wswV, bvF);
        k_mm3<<<GT, 256, 0, stream>>>(ht, WqS1, bq1, qb, wswK, bkF, kA, wswV, bvF, vM, NT);

        // C. aggregate r1 into agg (dst = v)
        k_node_attn<<<(NV + 3) / 4, 256, 0, stream>>>(qv, kA, vM, rp_tv, es_tv, P1, scale, agg, NV);

        // D. update hv (old hv fully consumed)
        k_mm<2, 1><<<GV, 256, 0, stream>>>(agg, WaS0, ba + (l * 2 + 0) * HID, hv, skip + (l * 2 + 0), NV);

        // E. r2 (t->t) projections from OLD ht (kA/vM from r1 dead after C)
        k_fuse_w2<<<2 * NH, 256, 0, stream>>>(Wk1, bk1, A2, wswK2, bkF2, Wv1, bv1, M2, wswV2, bvF2);
        k_mm2<<<GT, 256, 0, stream>>>(ht, wswK2, bkF2, kA, wswV2, bvF2, vM, NT);

        // F. combined dst=t aggregation: r0 (kA0/vM0) + r2 (kA/vM)
        k_node_attn2<<<(NT + 3) / 4, 256, 0, stream>>>(qb, kA0, vM0, rp_vt, es_vt, P0,
                                                       kA, vM, rp_tt, es_tt, P2, scale, agg, NT);

        // G. update ht. Layer 1: ht is consumed ONLY by tpart -> fuse update+tpart,
        //    skip the global ht write entirely (k_mm_gt writes tpart into kA, dead after F).
        if (l == 0) {
            k_mm<2, 1><<<GT, 256, 0, stream>>>(agg, WaS1, ba + (l * 2 + 1) * HID, ht, skip + (l * 2 + 1), NT);
        } else {
            k_mm_gt<<<GT, 256, 0, stream>>>(agg, WaS1, ba + (l * 2 + 1) * HID, skip + (l * 2 + 1),
                                            ht, wswA + (size_t)8 * 65536, kA, NT);
        }
    }

    k_vpart<<<1, 256, 0, stream>>>(hv, current, Ws1, bs1, vp);
    k_final<<<2048, 256, 0, stream>>>(kA /*tpart*/, vp, Ws2, bs2, (float*)d_out);
}

// Round 21
// 976.868 us; speedup vs baseline: 1.1245x; 1.0130x over previous
//
#include <hip/hip_runtime.h>
#include <hip/hip_bf16.h>
#include <math.h>

#define HID 256
#define NH 8
#define DH 32
#define NL 2
#define NV 20000
#define NT 50000
#define NE 100000
#define NC 8
#define FIN 64

typedef unsigned short u16;
typedef unsigned int u32;
typedef short s16x8 __attribute__((ext_vector_type(8)));
typedef float f32x4 __attribute__((ext_vector_type(4)));

__device__ __forceinline__ float bf2f(u16 u) { return __uint_as_float(((u32)u) << 16); }
__device__ __forceinline__ u16 f2bf(float f) {
    u32 x = __float_as_uint(f);
    u32 r = ((x >> 16) & 1u) + 0x7fffu;
    return (u16)((x + r) >> 16);
}
__device__ __forceinline__ void up2(u32 u, float& a, float& b) {
    a = __uint_as_float(u << 16);
    b = __uint_as_float(u & 0xffff0000u);
}
__device__ __forceinline__ s16x8 gelu8(s16x8 a) {
    s16x8 r;
#pragma unroll
    for (int i = 0; i < 8; i++) {
        float v = bf2f((u16)a[i]);
        v = 0.5f * v * (1.f + erff(v * 0.70710678118654752f));
        r[i] = (short)f2bf(v);
    }
    return r;
}

// ---------------- zero fill ----------------
__global__ void k_zero_i(int* __restrict__ p, int n) {
    for (int i = blockIdx.x * 256 + threadIdx.x; i < n; i += gridDim.x * 256) p[i] = 0;
}

// ---------------- batched histogram of 3 dst arrays ----------------
__global__ void k_hist3(const int* __restrict__ d0, const int* __restrict__ d1, const int* __restrict__ d2,
                        int* __restrict__ cnt3) {
    int r = blockIdx.x >> 9;        // 0..2
    int b = blockIdx.x & 511;
    const int* dst = (r == 0) ? d0 : (r == 1) ? d1 : d2;
    int* cnt = cnt3 + (size_t)r * NT;
    for (int e = b * 256 + threadIdx.x; e < NE; e += 512 * 256)
        atomicAdd(&cnt[dst[e]], 1);
}

// ---------------- batched serial scans ----------------
__global__ __launch_bounds__(1024) void k_scan3(const int* __restrict__ cnt3,
                                                int* __restrict__ rp0, int* __restrict__ rp1, int* __restrict__ rp2) {
    int r = blockIdx.x;
    const int* cnt = cnt3 + (size_t)r * NT;
    int* rp = (r == 0) ? rp0 : (r == 1) ? rp1 : rp2;
    int n = (r == 1) ? NV : NT;
    __shared__ int wsum[16];
    __shared__ int carry_s;
    int t = threadIdx.x, lane = t & 63, wv = t >> 6;
    if (t == 0) { carry_s = 0; rp[0] = 0; }
    __syncthreads();
    for (int base = 0; base < n; base += 1024) {
        int v = (base + t < n) ? cnt[base + t] : 0;
        int x = v;
#pragma unroll
        for (int off = 1; off < 64; off <<= 1) {
            int y = __shfl_up(x, off, 64);
            if (lane >= off) x += y;
        }
        if (lane == 63) wsum[wv] = x;
        __syncthreads();
        if (wv == 0 && lane < 16) {
            int s = wsum[lane];
#pragma unroll
            for (int off = 1; off < 16; off <<= 1) {
                int y = __shfl_up(s, off, 64);
                if (lane >= off) s += y;
            }
            wsum[lane] = s;
        }
        __syncthreads();
        int prefix = carry_s + (wv > 0 ? wsum[wv - 1] : 0);
        if (base + t < n) rp[base + t + 1] = prefix + x;
        __syncthreads();
        if (t == 0) carry_s += wsum[15];
        __syncthreads();
    }
}

// ---------------- batched fill copy ----------------
__global__ void k_copy3(const int* __restrict__ rp0, const int* __restrict__ rp1, const int* __restrict__ rp2,
                        int* __restrict__ fill3) {
    int r = blockIdx.x >> 8;
    int b = blockIdx.x & 255;
    const int* rp = (r == 0) ? rp0 : (r == 1) ? rp1 : rp2;
    int n = (r == 1) ? NV : NT;
    int* fill = fill3 + (size_t)r * NT;
    for (int i = b * 256 + threadIdx.x; i < n; i += 256 * 256) fill[i] = rp[i];
}

// ---------------- batched scatter ----------------
__global__ void k_scatter3(const int* __restrict__ d0, const int* __restrict__ s0,
                           const int* __restrict__ d1, const int* __restrict__ s1,
                           const int* __restrict__ d2, const int* __restrict__ s2,
                           int* __restrict__ fill3,
                           int* __restrict__ es0, int* __restrict__ es1, int* __restrict__ es2) {
    int r = blockIdx.x >> 9;
    int b = blockIdx.x & 511;
    const int* dst = (r == 0) ? d0 : (r == 1) ? d1 : d2;
    const int* src = (r == 0) ? s0 : (r == 1) ? s1 : s2;
    int* fill = fill3 + (size_t)r * NT;
    int* es = (r == 0) ? es0 : (r == 1) ? es1 : es2;
    for (int e = b * 256 + threadIdx.x; e < NE; e += 512 * 256) {
        int d = dst[e];
        int p = atomicAdd(&fill[d], 1);
        es[p] = src[e];
    }
}

// ---------------- input projection ----------------
__global__ __launch_bounds__(256) void k_in_proj(const float* __restrict__ X, const float* __restrict__ W,
                          const float* __restrict__ b, u16* __restrict__ Y, int N) {
    const int NPB = 16;
    __shared__ float xs[NPB][FIN];
    int n0 = blockIdx.x * NPB;
    int t = threadIdx.x;
    for (int idx = t; idx < NPB * FIN; idx += 256) {
        int i = idx >> 6, c = idx & 63;
        int n = n0 + i;
        xs[i][c] = (n < N) ? X[(size_t)n * FIN + c] : 0.f;
    }
    __syncthreads();
    float acc[NPB];
#pragma unroll
    for (int i = 0; i < NPB; i++) acc[i] = 0.f;
    for (int c = 0; c < FIN; c++) {
        float w = W[c * HID + t];
#pragma unroll
        for (int i = 0; i < NPB; i++) acc[i] += xs[i][c] * w;
    }
    float bb = b[t];
    for (int i = 0; i < NPB; i++) {
        int n = n0 + i;
        if (n < N) Y[(size_t)n * HID + t] = f2bf(fmaxf(acc[i] + bb, 0.f));
    }
}

// swizzle index for MFMA B fragment
__device__ __forceinline__ int swz_idx(int k, int n) {
    int ks = k >> 5, r = k & 31;
    int j = r & 7;
    int l = ((r >> 3) << 4) | (n & 15);
    int nt = n >> 4;
    return ((ks * 16 + nt) * 64 + l) * 8 + j;
}

// ---------------- dual fuse: k and v weight pairs in one launch (16 blocks) ----------------
__global__ __launch_bounds__(256) void k_fuse_w2(
        const float* __restrict__ Wk_, const float* __restrict__ bk_, const float* __restrict__ Rk,
        u16* __restrict__ WswK, float* __restrict__ bkO,
        const float* __restrict__ Wv_, const float* __restrict__ bv_, const float* __restrict__ Rv,
        u16* __restrict__ WswV, float* __restrict__ bvO) {
    int h = blockIdx.x & 7;
    int which = blockIdx.x >> 3;
    const float* W = which ? Wv_ : Wk_;
    const float* b = which ? bv_ : bk_;
    const float* R = which ? Rv : Rk;
    u16* Wsw = which ? WswV : WswK;
    float* bout = which ? bvO : bkO;
    __shared__ float sR[DH * DH];
    int t = threadIdx.x;
    for (int idx = t; idx < DH * DH; idx += 256) sR[idx] = R[h * DH * DH + idx];
    __syncthreads();
    int f = t & 31, c0 = t >> 5;
    for (int c = c0; c < HID; c += 8) {
        float acc = 0.f;
#pragma unroll
        for (int d = 0; d < DH; d++) acc += W[c * HID + h * DH + d] * sR[d * DH + f];
        Wsw[swz_idx(c, h * DH + f)] = f2bf(acc);
    }
    if (t < DH) {
        float acc = 0.f;
#pragma unroll
        for (int d = 0; d < DH; d++) acc += b[h * DH + d] * sR[d * DH + t];
        bout[h * DH + t] = acc;
    }
}

// ---------------- batched swizzle of 9 static weights ----------------
__global__ __launch_bounds__(256) void k_swz_multi(const float* __restrict__ Wq, const float* __restrict__ Wa,
                                                   const float* __restrict__ Ws1, u16* __restrict__ out) {
    int slot = blockIdx.x >> 8;
    int idx = ((blockIdx.x & 255) << 8) | threadIdx.x;
    const float* src = (slot < 4) ? (Wq + (size_t)slot * 65536)
                     : (slot < 8) ? (Wa + (size_t)(slot - 4) * 65536)
                                  : Ws1;
    int j = idx & 7, l = (idx >> 3) & 63, nt = (idx >> 9) & 15, ks = idx >> 13;
    int k = ks * 32 + (l >> 4) * 8 + j;
    int n = nt * 16 + (l & 15);
    out[(size_t)slot * 65536 + idx] = f2bf(src[k * HID + n]);
}

// ---------------- MFMA GEMM, slim-wave ----------------
// MODE 0: bf16+bias. MODE 1: f32, no bias. MODE 2: skip-mix bf16. MODE 3: bf16, no bias.
template <int MODE, int GELU>
__global__ __launch_bounds__(256) void k_mm(const u16* __restrict__ X, const u16* __restrict__ Wsw,
                                            const float* __restrict__ bias, void* __restrict__ Y,
                                            const float* __restrict__ skip_, int N) {
    int tid = threadIdx.x;
    int w = tid >> 6, lane = tid & 63;
    int r0 = blockIdx.x * 16;
    int rA = r0 + (lane & 15);
    int koffg = lane >> 4;
    s16x8 a[8];
    if (rA < N) {
        const s16x8* ap = (const s16x8*)(X + (size_t)rA * HID) + koffg;
#pragma unroll
        for (int ks = 0; ks < 8; ks++) a[ks] = ap[ks * 4];
    } else {
#pragma unroll
        for (int ks = 0; ks < 8; ks++) a[ks] = (s16x8){0, 0, 0, 0, 0, 0, 0, 0};
    }
    if (GELU) {
#pragma unroll
        for (int ks = 0; ks < 8; ks++) a[ks] = gelu8(a[ks]);
    }
    f32x4 acc[4];
#pragma unroll
    for (int nt = 0; nt < 4; nt++) acc[nt] = (f32x4){0.f, 0.f, 0.f, 0.f};
    const s16x8* wp = (const s16x8*)Wsw;
#pragma unroll
    for (int ks = 0; ks < 8; ks++) {
        const s16x8* wq = wp + (size_t)ks * 16 * 64 + lane;
#pragma unroll
        for (int nt = 0; nt < 4; nt++) {
            s16x8 b = wq[(w * 4 + nt) * 64];
            acc[nt] = __builtin_amdgcn_mfma_f32_16x16x32_bf16(a[ks], b, acc[nt], 0, 0, 0);
        }
    }
    int colb = lane & 15;
    int rowb = r0 + koffg * 4;
    float beta = 0.f, ombeta = 0.f;
    if (MODE == 2) { beta = 1.f / (1.f + expf(-skip_[0])); ombeta = 1.f - beta; }
#pragma unroll
    for (int nt = 0; nt < 4; nt++) {
        int col = w * 64 + nt * 16 + colb;
        float bb = (MODE == 1 || MODE == 3) ? 0.f : bias[col];
#pragma unroll
        for (int j = 0; j < 4; j++) {
            int row = rowb + j;
            if (row < N) {
                float v = acc[nt][j] + bb;
                if (MODE == 0 || MODE == 3) {
                    ((u16*)Y)[(size_t)row * HID + col] = f2bf(v);
                } else if (MODE == 1) {
                    ((float*)Y)[(size_t)row * HID + col] = v;
                } else {
                    u16* hp = (u16*)Y + (size_t)row * HID + col;
                    *hp = f2bf(beta * v + ombeta * bf2f(*hp));
                }
            }
        }
    }
}

// ---------------- fused ht-update + tpart GEMM (layer 1 step G) ----------------
__global__ __launch_bounds__(256) void k_mm_gt(const u16* __restrict__ agg, const u16* __restrict__ WaSw,
                                               const float* __restrict__ ba_, const float* __restrict__ skip_,
                                               const u16* __restrict__ ht_old, const u16* __restrict__ Ws1Sw,
                                               u16* __restrict__ tpart, int N) {
    __shared__ u16 sH[16][264];
    int tid = threadIdx.x;
    int w = tid >> 6, lane = tid & 63;
    int r0 = blockIdx.x * 16;
    int rA = r0 + (lane & 15);
    int koffg = lane >> 4;
    s16x8 a[8];
    {
        const s16x8* ap = (const s16x8*)(agg + (size_t)rA * HID) + koffg;
#pragma unroll
        for (int ks = 0; ks < 8; ks++) a[ks] = gelu8(ap[ks * 4]);
    }
    f32x4 acc[4];
#pragma unroll
    for (int nt = 0; nt < 4; nt++) acc[nt] = (f32x4){0.f, 0.f, 0.f, 0.f};
    const s16x8* wp = (const s16x8*)WaSw;
#pragma unroll
    for (int ks = 0; ks < 8; ks++) {
        const s16x8* wq = wp + (size_t)ks * 16 * 64 + lane;
#pragma unroll
        for (int nt = 0; nt < 4; nt++)
            acc[nt] = __builtin_amdgcn_mfma_f32_16x16x32_bf16(a[ks], wq[(w * 4 + nt) * 64], acc[nt], 0, 0, 0);
    }
    float beta = 1.f / (1.f + expf(-skip_[0])), ombeta = 1.f - beta;
    int colb = lane & 15;
    int rowl = koffg * 4;
#pragma unroll
    for (int nt = 0; nt < 4; nt++) {
        int col = w * 64 + nt * 16 + colb;
        float bb = ba_[col];
#pragma unroll
        for (int j = 0; j < 4; j++) {
            int row = r0 + rowl + j;
            float v = acc[nt][j] + bb;
            float o = beta * v + ombeta * bf2f(ht_old[(size_t)row * HID + col]);
            sH[rowl + j][col] = f2bf(o);
        }
    }
    __syncthreads();
    s16x8 a2[8];
#pragma unroll
    for (int ks = 0; ks < 8; ks++)
        a2[ks] = *(const s16x8*)&sH[lane & 15][ks * 32 + koffg * 8];
#pragma unroll
    for (int nt = 0; nt < 4; nt++) acc[nt] = (f32x4){0.f, 0.f, 0.f, 0.f};
    const s16x8* wp2 = (const s16x8*)Ws1Sw;
#pragma unroll
    for (int ks = 0; ks < 8; ks++) {
        const s16x8* wq = wp2 + (size_t)ks * 16 * 64 + lane;
#pragma unroll
        for (int nt = 0; nt < 4; nt++)
            acc[nt] = __builtin_amdgcn_mfma_f32_16x16x32_bf16(a2[ks], wq[(w * 4 + nt) * 64], acc[nt], 0, 0, 0);
    }
#pragma unroll
    for (int nt = 0; nt < 4; nt++) {
        int col = w * 64 + nt * 16 + colb;
#pragma unroll
        for (int j = 0; j < 4; j++) {
            int row = r0 + rowl + j;
            if (row < N) tpart[(size_t)row * HID + col] = f2bf(acc[nt][j]);
        }
    }
}

// ---------------- dual-B slim-wave MFMA GEMM ----------------
__global__ __launch_bounds__(256) void k_mm2(const u16* __restrict__ X,
                                             const u16* __restrict__ W1, const float* __restrict__ b1, u16* __restrict__ Y1,
                                             const u16* __restrict__ W2, const float* __restrict__ b2, u16* __restrict__ Y2,
                                             int N) {
    int tid = threadIdx.x;
    int w = tid >> 6, lane = tid & 63;
    int r0 = blockIdx.x * 16;
    int rA = r0 + (lane & 15);
    int koffg = lane >> 4;
    s16x8 a[8];
    if (rA < N) {
        const s16x8* ap = (const s16x8*)(X + (size_t)rA * HID) + koffg;
#pragma unroll
        for (int ks = 0; ks < 8; ks++) a[ks] = ap[ks * 4];
    } else {
#pragma unroll
        for (int ks = 0; ks < 8; ks++) a[ks] = (s16x8){0, 0, 0, 0, 0, 0, 0, 0};
    }
    int colb = lane & 15;
    int rowb = r0 + koffg * 4;
#pragma unroll
    for (int pass = 0; pass < 2; pass++) {
        const u16* Wsw = pass ? W2 : W1;
        const float* bias = pass ? b2 : b1;
        u16* Y = pass ? Y2 : Y1;
        f32x4 acc[4];
#pragma unroll
        for (int nt = 0; nt < 4; nt++) acc[nt] = (f32x4){0.f, 0.f, 0.f, 0.f};
        const s16x8* wp = (const s16x8*)Wsw;
#pragma unroll
        for (int ks = 0; ks < 8; ks++) {
            const s16x8* wq = wp + (size_t)ks * 16 * 64 + lane;
#pragma unroll
            for (int nt = 0; nt < 4; nt++) {
                s16x8 b = wq[(w * 4 + nt) * 64];
                acc[nt] = __builtin_amdgcn_mfma_f32_16x16x32_bf16(a[ks], b, acc[nt], 0, 0, 0);
            }
        }
#pragma unroll
        for (int nt = 0; nt < 4; nt++) {
            int col = w * 64 + nt * 16 + colb;
            float bb = bias[col];
#pragma unroll
            for (int j = 0; j < 4; j++) {
                int row = rowb + j;
                if (row < N) Y[(size_t)row * HID + col] = f2bf(acc[nt][j] + bb);
            }
        }
    }
}

// ---------------- triple-B slim-wave MFMA GEMM ----------------
__global__ __launch_bounds__(256) void k_mm3(const u16* __restrict__ X,
                                             const u16* __restrict__ W0, const float* __restrict__ b0, u16* __restrict__ Y0,
                                             const u16* __restrict__ W1, const float* __restrict__ b1, u16* __restrict__ Y1,
                                             const u16* __restrict__ W2, const float* __restrict__ b2, u16* __restrict__ Y2,
                                             int N) {
    int tid = threadIdx.x;
    int w = tid >> 6, lane = tid & 63;
    int r0 = blockIdx.x * 16;
    int rA = r0 + (lane & 15);
    int koffg = lane >> 4;
    s16x8 a[8];
    if (rA < N) {
        const s16x8* ap = (const s16x8*)(X + (size_t)rA * HID) + koffg;
#pragma unroll
        for (int ks = 0; ks < 8; ks++) a[ks] = ap[ks * 4];
    } else {
#pragma unroll
        for (int ks = 0; ks < 8; ks++) a[ks] = (s16x8){0, 0, 0, 0, 0, 0, 0, 0};
    }
    int colb = lane & 15;
    int rowb = r0 + koffg * 4;
#pragma unroll
    for (int pass = 0; pass < 3; pass++) {
        const u16* Wsw = (pass == 0) ? W0 : (pass == 1) ? W1 : W2;
        const float* bias = (pass == 0) ? b0 : (pass == 1) ? b1 : b2;
        u16* Y = (pass == 0) ? Y0 : (pass == 1) ? Y1 : Y2;
        f32x4 acc[4];
#pragma unroll
        for (int nt = 0; nt < 4; nt++) acc[nt] = (f32x4){0.f, 0.f, 0.f, 0.f};
        const s16x8* wp = (const s16x8*)Wsw;
#pragma unroll
        for (int ks = 0; ks < 8; ks++) {
            const s16x8* wq = wp + (size_t)ks * 16 * 64 + lane;
#pragma unroll
            for (int nt = 0; nt < 4; nt++) {
                s16x8 b = wq[(w * 4 + nt) * 64];
                acc[nt] = __builtin_amdgcn_mfma_f32_16x16x32_bf16(a[ks], b, acc[nt], 0, 0, 0);
            }
        }
#pragma unroll
        for (int nt = 0; nt < 4; nt++) {
            int col = w * 64 + nt * 16 + colb;
            float bb = bias[col];
#pragma unroll
            for (int j = 0; j < 4; j++) {
                int row = rowb + j;
                if (row < N) Y[(size_t)row * HID + col] = f2bf(acc[nt][j] + bb);
            }
        }
    }
}

// ---------------- online-softmax over one CSR, 2-deep prefetch ----------------
__device__ __forceinline__ void attn_pass(const u16* __restrict__ kA, const u16* __restrict__ vM,
                                          const int* __restrict__ es, int jb, int je,
                                          float q0, float q1, float q2, float q3, float ph, int lane4,
                                          float& o0, float& o1, float& o2, float& o3) {
    float m = -INFINITY, ss = 0.f, a0 = 0.f, a1 = 0.f, a2 = 0.f, a3 = 0.f;
    uint2 ku0 = {0, 0}, vu0 = {0, 0}, ku1 = {0, 0}, vu1 = {0, 0};
    if (jb < je) {
        int s = es[jb];
        ku0 = *(const uint2*)(kA + (size_t)s * HID + lane4);
        vu0 = *(const uint2*)(vM + (size_t)s * HID + lane4);
    }
    if (jb + 1 < je) {
        int s = es[jb + 1];
        ku1 = *(const uint2*)(kA + (size_t)s * HID + lane4);
        vu1 = *(const uint2*)(vM + (size_t)s * HID + lane4);
    }
    for (int j = jb; j < je; j++) {
        uint2 ku = ku0, vu = vu0;
        ku0 = ku1; vu0 = vu1;
        if (j + 2 < je) {
            int s = es[j + 2];
            ku1 = *(const uint2*)(kA + (size_t)s * HID + lane4);
            vu1 = *(const uint2*)(vM + (size_t)s * HID + lane4);
        }
        float k0, k1, k2, k3; up2(ku.x, k0, k1); up2(ku.y, k2, k3);
        float part = q0 * k0 + q1 * k1 + q2 * k2 + q3 * k3;
        part += __shfl_xor(part, 1, 64);
        part += __shfl_xor(part, 2, 64);
        part += __shfl_xor(part, 4, 64);
        float logit = part * ph;
        float nm = fmaxf(m, logit);
        float corr = expf(m - nm);
        float ee = expf(logit - nm);
        float v0, v1, v2, v3; up2(vu.x, v0, v1); up2(vu.y, v2, v3);
        ss = ss * corr + ee;
        a0 = a0 * corr + ee * v0; a1 = a1 * corr + ee * v1;
        a2 = a2 * corr + ee * v2; a3 = a3 * corr + ee * v3;
        m = nm;
    }
    float inv = 1.f / (ss + 1e-16f);
    o0 += a0 * inv; o1 += a1 * inv; o2 += a2 * inv; o3 += a3 * inv;
}

// ---------------- single-relation node attention ----------------
__global__ __launch_bounds__(256) void k_node_attn(
        const u16* __restrict__ q, const u16* __restrict__ kA, const u16* __restrict__ vM,
        const int* __restrict__ rp, const int* __restrict__ es,
        const float* __restrict__ P, float scale,
        u16* __restrict__ agg, int Nd) {
    int node = blockIdx.x * 4 + (threadIdx.x >> 6);
    if (node >= Nd) return;
    int lane = threadIdx.x & 63;
    float ph = P[lane >> 3] * scale;
    uint2 qu = *(const uint2*)(q + (size_t)node * HID + lane * 4);
    float q0, q1, q2, q3; up2(qu.x, q0, q1); up2(qu.y, q2, q3);
    float o0 = 0.f, o1 = 0.f, o2 = 0.f, o3 = 0.f;
    attn_pass(kA, vM, es, rp[node], rp[node + 1], q0, q1, q2, q3, ph, lane * 4, o0, o1, o2, o3);
    u16* ap = agg + (size_t)node * HID + lane * 4;
    ap[0] = f2bf(o0); ap[1] = f2bf(o1); ap[2] = f2bf(o2); ap[3] = f2bf(o3);
}

// ---------------- 8-node attention into compact agg8 ----------------
__global__ __launch_bounds__(256) void k_attn8(
        const u16* __restrict__ q8, const u16* __restrict__ kA, const u16* __restrict__ vM,
        const int* __restrict__ rp, const int* __restrict__ es, const int* __restrict__ current,
        const float* __restrict__ P, float scale, u16* __restrict__ agg8) {
    int wv = blockIdx.x * 4 + (threadIdx.x >> 6);
    if (wv >= NC) return;
    int node = current[wv * 2];
    int lane = threadIdx.x & 63;
    int lane4 = lane * 4;
    float ph = P[lane >> 3] * scale;
    uint2 qu = *(const uint2*)(q8 + (size_t)wv * HID + lane4);
    float q0, q1, q2, q3; up2(qu.x, q0, q1); up2(qu.y, q2, q3);
    float o0 = 0.f, o1 = 0.f, o2 = 0.f, o3 = 0.f;
    attn_pass(kA, vM, es, rp[node], rp[node + 1], q0, q1, q2, q3, ph, lane4, o0, o1, o2, o3);
    u16* ap = agg8 + (size_t)wv * HID + lane4;
    ap[0] = f2bf(o0); ap[1] = f2bf(o1); ap[2] = f2bf(o2); ap[3] = f2bf(o3);
}

// ---------------- q rows for the 8 current nodes (f32 weights) ----------------
__global__ __launch_bounds__(256) void k_q8(const u16* __restrict__ hv, const int* __restrict__ current,
                                            const float* __restrict__ Wq_, const float* __restrict__ bq_,
                                            u16* __restrict__ q8) {
    __shared__ float row[HID];
    int t = threadIdx.x;
    for (int c = 0; c < NC; c++) {
        int n = current[c * 2];
        row[t] = bf2f(hv[(size_t)n * HID + t]);
        __syncthreads();
        float acc = 0.f;
        for (int i = 0; i < HID; i++) acc += row[i] * Wq_[i * HID + t];
        q8[c * HID + t] = f2bf(acc + bq_[t]);
        __syncthreads();
    }
}

// ---------------- dual-relation node attention (dst=t: r0 + r2, f32 sum) ----------------
__global__ __launch_bounds__(256) void k_node_attn2(
        const u16* __restrict__ q,
        const u16* __restrict__ kA0, const u16* __restrict__ vM0,
        const int* __restrict__ rp0, const int* __restrict__ es0, const float* __restrict__ P0,
        const u16* __restrict__ kA1, const u16* __restrict__ vM1,
        const int* __restrict__ rp1, const int* __restrict__ es1, const float* __restrict__ P1,
        float scale, u16* __restrict__ agg, int Nd) {
    int node = blockIdx.x * 4 + (threadIdx.x >> 6);
    if (node >= Nd) return;
    int lane = threadIdx.x & 63;
    int h = lane >> 3;
    int lane4 = lane * 4;
    float ph0 = P0[h] * scale, ph1 = P1[h] * scale;
    uint2 qu = *(const uint2*)(q + (size_t)node * HID + lane4);
    float q0, q1, q2, q3; up2(qu.x, q0, q1); up2(qu.y, q2, q3);
    float o0 = 0.f, o1 = 0.f, o2 = 0.f, o3 = 0.f;
    attn_pass(kA0, vM0, es0, rp0[node], rp0[node + 1], q0, q1, q2, q3, ph0, lane4, o0, o1, o2, o3);
    attn_pass(kA1, vM1, es1, rp1[node], rp1[node + 1], q0, q1, q2, q3, ph1, lane4, o0, o1, o2, o3);
    u16* ap = agg + (size_t)node * HID + lane4;
    ap[0] = f2bf(o0); ap[1] = f2bf(o1); ap[2] = f2bf(o2); ap[3] = f2bf(o3);
}

// ---------------- fused l=1 hv-update (8 rows) + vpart ----------------
// o_c = beta*(gelu(agg8_c)@Wa + ba) + (1-beta)*hv_old[n_c]  (bf16-rounded)
// vpart_c = o_c @ Ws1[256:] + bs1
__global__ __launch_bounds__(256) void k_vpart_f(
        const u16* __restrict__ agg8, const float* __restrict__ Wa_, const float* __restrict__ ba_,
        const float* __restrict__ skip_, const u16* __restrict__ hv, const int* __restrict__ current,
        const float* __restrict__ Ws1, const float* __restrict__ bs1, float* __restrict__ vpart) {
    __shared__ float sG[NC][HID];
    int t = threadIdx.x;
#pragma unroll
    for (int c = 0; c < NC; c++) {
        float x = bf2f(agg8[c * HID + t]);
        sG[c][t] = 0.5f * x * (1.f + erff(x * 0.70710678118654752f));
    }
    __syncthreads();
    float acc[NC];
#pragma unroll
    for (int c = 0; c < NC; c++) acc[c] = 0.f;
    for (int i = 0; i < HID; i++) {
        float wv_ = Wa_[i * HID + t];
#pragma unroll
        for (int c = 0; c < NC; c++) acc[c] += sG[c][i] * wv_;
    }
    float beta = 1.f / (1.f + expf(-skip_[0])), ombeta = 1.f - beta;
    float bb = ba_[t];
    __syncthreads();
#pragma unroll
    for (int c = 0; c < NC; c++) {
        int n = current[c * 2];
        float o = beta * (acc[c] + bb) + ombeta * bf2f(hv[(size_t)n * HID + t]);
        sG[c][t] = bf2f(f2bf(o)); // preserve prior bf16 rounding point
    }
    __syncthreads();
    float acc2[NC];
#pragma unroll
    for (int c = 0; c < NC; c++) acc2[c] = 0.f;
    for (int i = 0; i < HID; i++) {
        float w1 = Ws1[(size_t)(HID + i) * HID + t];
#pragma unroll
        for (int c = 0; c < NC; c++) acc2[c] += sG[c][i] * w1;
    }
    float bs = bs1[t];
#pragma unroll
    for (int c = 0; c < NC; c++) vpart[c * HID + t] = acc2[c] + bs;
}

// ---------------- final: tpart bf16 ----------------
__global__ __launch_bounds__(256) void k_final(const u16* __restrict__ tpart, const float* __restrict__ vpart,
                        const float* __restrict__ Ws2, const float* __restrict__ bs2,
                        float* __restrict__ out) {
    __shared__ float vp[NC * HID];
    int t = threadIdx.x;
    for (int idx = t; idx < NC * HID; idx += 256) vp[idx] = vpart[idx];
    __syncthreads();
    int lane = t & 63, w = t >> 6;
    float w20[4], w21[4];
#pragma unroll
    for (int i = 0; i < 4; i++) {
        w20[i] = Ws2[(lane + 64 * i) * 2 + 0];
        w21[i] = Ws2[(lane + 64 * i) * 2 + 1];
    }
    float b0 = bs2[0], b1 = bs2[1];
    for (int n = blockIdx.x * 4 + w; n < NT; n += gridDim.x * 4) {
        float tp[4];
#pragma unroll
        for (int i = 0; i < 4; i++) tp[i] = bf2f(tpart[(size_t)n * HID + lane + 64 * i]);
#pragma unroll
        for (int c = 0; c < NC; c++) {
            float a0 = 0.f, a1 = 0.f;
#pragma unroll
            for (int i = 0; i < 4; i++) {
                float hm = fmaxf(tp[i] + vp[c * HID + lane + 64 * i], 0.f);
                a0 += hm * w20[i];
                a1 += hm * w21[i];
            }
#pragma unroll
            for (int off = 32; off >= 1; off >>= 1) {
                a0 += __shfl_xor(a0, off, 64);
                a1 += __shfl_xor(a1, off, 64);
            }
            if (lane == 0) {
                out[(size_t)c * NT + n] = a0 + b0;
                float z = a1 + b1;
                out[(size_t)NC * NT + (size_t)c * NT + n] = 1.f / (1.f + expf(-z));
            }
        }
    }
}

extern "C" void kernel_launch(void* const* d_in, const int* in_sizes, int n_in,
                              void* d_out, int out_size, void* d_ws, size_t ws_size,
                              hipStream_t stream) {
    (void)in_sizes; (void)n_in; (void)out_size;
    const float* x_v    = (const float*)d_in[0];
    const float* x_t    = (const float*)d_in[1];
    const int* ei_vt_s  = (const int*)d_in[2];
    const int* ei_vt_d  = (const int*)d_in[3];
    const int* ei_tv_s  = (const int*)d_in[4];
    const int* ei_tv_d  = (const int*)d_in[5];
    const int* ei_tt_s  = (const int*)d_in[6];
    const int* ei_tt_d  = (const int*)d_in[7];
    const int* current  = (const int*)d_in[8];
    const float* W_in_v = (const float*)d_in[9];
    const float* b_in_v = (const float*)d_in[10];
    const float* W_in_t = (const float*)d_in[11];
    const float* b_in_t = (const float*)d_in[12];
    const float* Wk     = (const float*)d_in[13];
    const float* bk     = (const float*)d_in[14];
    const float* Wq     = (const float*)d_in[15];
    const float* bq     = (const float*)d_in[16];
    const float* Wv     = (const float*)d_in[17];
    const float* bv     = (const float*)d_in[18];
    const float* Wa     = (const float*)d_in[19];
    const float* ba     = (const float*)d_in[20];
    const float* skip   = (const float*)d_in[21];
    const float* a_rel  = (const float*)d_in[22];
    const float* m_rel  = (const float*)d_in[23];
    const float* p_rel  = (const float*)d_in[24];
    const float* Ws1    = (const float*)d_in[25];
    const float* bs1    = (const float*)d_in[26];
    const float* Ws2    = (const float*)d_in[27];
    const float* bs2    = (const float*)d_in[28];

    char* p = (char*)d_ws;
    auto alloc = [&](size_t bytes) -> char* {
        char* r = p;
        p += (bytes + 255) & ~(size_t)255;
        return r;
    };
    u16* hv   = (u16*)alloc((size_t)NV * HID * 2);
    u16* ht   = (u16*)alloc((size_t)NT * HID * 2);
    u16* qb   = (u16*)alloc((size_t)NT * HID * 2);
    u16* qv   = (u16*)alloc((size_t)NV * HID * 2);
    u16* kA   = (u16*)alloc((size_t)NT * HID * 2); // reused as bf16 tpart by k_mm_gt (after F)
    u16* vM   = (u16*)alloc((size_t)NT * HID * 2);
    u16* kA0  = (u16*)alloc((size_t)NV * HID * 2);
    u16* vM0  = (u16*)alloc((size_t)NV * HID * 2);
    u16* agg  = (u16*)alloc((size_t)NT * HID * 2);
    int* rp_vt = (int*)alloc((size_t)(NT + 1) * 4);
    int* rp_tv = (int*)alloc((size_t)(NV + 1) * 4);
    int* rp_tt = (int*)alloc((size_t)(NT + 1) * 4);
    int* es_vt = (int*)alloc((size_t)NE * 4);
    int* es_tv = (int*)alloc((size_t)NE * 4);
    int* es_tt = (int*)alloc((size_t)NE * 4);
    int* cnt3  = (int*)alloc((size_t)3 * NT * 4);
    int* fill3 = (int*)alloc((size_t)3 * NT * 4);
    float* vp  = (float*)alloc((size_t)NC * HID * 4);
    u16* q8   = (u16*)alloc((size_t)NC * HID * 2);
    u16* agg8 = (u16*)alloc((size_t)NC * HID * 2);
    float* bkF = (float*)alloc(HID * 4);
    float* bvF = (float*)alloc(HID * 4);
    u16*  wswK = (u16*)alloc((size_t)HID * HID * 2);
    u16*  wswV = (u16*)alloc((size_t)HID * HID * 2);
    u16*  wswK2 = (u16*)alloc((size_t)HID * HID * 2);
    u16*  wswV2 = (u16*)alloc((size_t)HID * HID * 2);
    float* bkF2 = (float*)alloc(HID * 4);
    float* bvF2 = (float*)alloc(HID * 4);
    u16*  wswA = (u16*)alloc((size_t)9 * HID * HID * 2);
    if ((size_t)(p - (char*)d_ws) > ws_size) return; // clean fail -> zeros signature

    const float scale = 0.17677669529663687f;

    // ---- build 3 CSRs (batched) ----
    k_zero_i<<<256, 256, 0, stream>>>(cnt3, 3 * NT);
    k_hist3<<<3 * 512, 256, 0, stream>>>(ei_vt_d, ei_tv_d, ei_tt_d, cnt3);
    k_scan3<<<3, 1024, 0, stream>>>(cnt3, rp_vt, rp_tv, rp_tt);
    k_copy3<<<3 * 256, 256, 0, stream>>>(rp_vt, rp_tv, rp_tt, fill3);
    k_scatter3<<<3 * 512, 256, 0, stream>>>(ei_vt_d, ei_vt_s, ei_tv_d, ei_tv_s, ei_tt_d, ei_tt_s,
                                            fill3, es_vt, es_tv, es_tt);

    // ---- swizzle all static weights in one launch ----
    k_swz_multi<<<9 * 256, 256, 0, stream>>>(Wq, Wa, Ws1, wswA);

    k_in_proj<<<(NV + 15) / 16, 256, 0, stream>>>(x_v, W_in_v, b_in_v, hv, NV);
    k_in_proj<<<(NT + 15) / 16, 256, 0, stream>>>(x_t, W_in_t, b_in_t, ht, NT);

    const int GV = (NV + 15) / 16, GT = (NT + 15) / 16;

    for (int l = 0; l < NL; l++) {
        const float* Wk0 = Wk + (size_t)(l * 2 + 0) * HID * HID;
        const float* Wk1 = Wk + (size_t)(l * 2 + 1) * HID * HID;
        const float* bk0 = bk + (l * 2 + 0) * HID, *bk1 = bk + (l * 2 + 1) * HID;
        const float* Wv0 = Wv + (size_t)(l * 2 + 0) * HID * HID;
        const float* Wv1 = Wv + (size_t)(l * 2 + 1) * HID * HID;
        const float* bv0 = bv + (l * 2 + 0) * HID, *bv1 = bv + (l * 2 + 1) * HID;
        const float* bq0 = bq + (l * 2 + 0) * HID, *bq1 = bq + (l * 2 + 1) * HID;
        const u16* WqS0 = wswA + (size_t)(l * 2 + 0) * 65536;
        const u16* WqS1 = wswA + (size_t)(l * 2 + 1) * 65536;
        const u16* WaS0 = wswA + (size_t)(4 + l * 2 + 0) * 65536;
        const u16* WaS1 = wswA + (size_t)(4 + l * 2 + 1) * 65536;
        const float* A0 = a_rel + (size_t)(l * 3 + 0) * NH * DH * DH;
        const float* A1 = a_rel + (size_t)(l * 3 + 1) * NH * DH * DH;
        const float* A2 = a_rel + (size_t)(l * 3 + 2) * NH * DH * DH;
        const float* M0 = m_rel + (size_t)(l * 3 + 0) * NH * DH * DH;
        const float* M1 = m_rel + (size_t)(l * 3 + 1) * NH * DH * DH;
        const float* M2 = m_rel + (size_t)(l * 3 + 2) * NH * DH * DH;
        const float* P0 = p_rel + (size_t)(l * 3 + 0) * NH;
        const float* P1 = p_rel + (size_t)(l * 3 + 1) * NH;
        const float* P2 = p_rel + (size_t)(l * 3 + 2) * NH;

        // A. r0 (v->t) weights; projections from OLD hv.
        k_fuse_w2<<<2 * NH, 256, 0, stream>>>(Wk0, bk0, A0, wswK, bkF, Wv0, bv0, M0, wswV, bvF);
        if (l == 0) {
            k_mm3<<<GV, 256, 0, stream>>>(hv, WqS0, bq0, qv, wswK, bkF, kA0, wswV, bvF, vM0, NV);
        } else {
            // l=1: q_v needed only for 8 nodes -> k+v only here, q8 tiny kernel below
            k_mm2<<<GV, 256, 0, stream>>>(hv, wswK, bkF, kA0, wswV, bvF, vM0, NV);
            k_q8<<<1, 256, 0, stream>>>(hv, current, Wq + (size_t)(l * 2 + 0) * HID * HID, bq0, q8);
        }

        // B. r1 (t->v) weights; fused q_t + k1 + v1 from OLD ht
        k_fuse_w2<<<2 * NH, 256, 0, stream>>>(Wk1, bk1, A1, wswK, bkF, Wv1, bv1, M1, wswV, bvF);
        k_mm3<<<GT, 256, 0, stream>>>(ht, WqS1, bq1, qb, wswK, bkF, kA, wswV, bvF, vM, NT);

        // C. aggregate r1 (dst = v)
        if (l == 0) {
            k_node_attn<<<(NV + 3) / 4, 256, 0, stream>>>(qv, kA, vM, rp_tv, es_tv, P1, scale, agg, NV);
            // D. update hv (full)
            k_mm<2, 1><<<GV, 256, 0, stream>>>(agg, WaS0, ba + (l * 2 + 0) * HID, hv, skip + (l * 2 + 0), NV);
        } else {
            // l=1: only 8 dst-v nodes are live -> compact agg8; hv update deferred into k_vpart_f
            k_attn8<<<2, 256, 0, stream>>>(q8, kA, vM, rp_tv, es_tv, current, P1, scale, agg8);
        }

        // E. r2 (t->t) projections from OLD ht (kA/vM from r1 dead after C)
        k_fuse_w2<<<2 * NH, 256, 0, stream>>>(Wk1, bk1, A2, wswK2, bkF2, Wv1, bv1, M2, wswV2, bvF2);
        k_mm2<<<GT, 256, 0, stream>>>(ht, wswK2, bkF2, kA, wswV2, bvF2, vM, NT);

        // F. combined dst=t aggregation: r0 (kA0/vM0) + r2 (kA/vM)
        k_node_attn2<<<(NT + 3) / 4, 256, 0, stream>>>(qb, kA0, vM0, rp_vt, es_vt, P0,
                                                       kA, vM, rp_tt, es_tt, P2, scale, agg, NT);

        // G. update ht. l=1: fuse update+tpart (ht write skipped; tpart -> kA).
        if (l == 0) {
            k_mm<2, 1><<<GT, 256, 0, stream>>>(agg, WaS1, ba + (l * 2 + 1) * HID, ht, skip + (l * 2 + 1), NT);
        } else {
            k_mm_gt<<<GT, 256, 0, stream>>>(agg, WaS1, ba + (l * 2 + 1) * HID, skip + (l * 2 + 1),
                                            ht, wswA + (size_t)8 * 65536, kA, NT);
        }
    }

    // fused l=1 hv-update (8 rows) + vpart (hv holds post-l0 values = hv_old for the mix)
    k_vpart_f<<<1, 256, 0, stream>>>(agg8, Wa + (size_t)2 * 65536, ba + 2 * HID, skip + 2,
                                     hv, current, Ws1, bs1, vp);
    k_final<<<2048, 256, 0, stream>>>(kA /*tpart*/, vp, Ws2, bs2, (float*)d_out);
}

// Round 22
// 971.918 us; speedup vs baseline: 1.1302x; 1.0051x over previous
//
#include <hip/hip_runtime.h>
#include <hip/hip_bf16.h>
#include <math.h>

#define HID 256
#define NH 8
#define DH 32
#define NL 2
#define NV 20000
#define NT 50000
#define NE 100000
#define NC 8
#define FIN 64

typedef unsigned short u16;
typedef unsigned int u32;
typedef short s16x8 __attribute__((ext_vector_type(8)));
typedef float f32x4 __attribute__((ext_vector_type(4)));

__device__ __forceinline__ float bf2f(u16 u) { return __uint_as_float(((u32)u) << 16); }
__device__ __forceinline__ u16 f2bf(float f) {
    u32 x = __float_as_uint(f);
    u32 r = ((x >> 16) & 1u) + 0x7fffu;
    return (u16)((x + r) >> 16);
}
__device__ __forceinline__ void up2(u32 u, float& a, float& b) {
    a = __uint_as_float(u << 16);
    b = __uint_as_float(u & 0xffff0000u);
}
__device__ __forceinline__ s16x8 gelu8(s16x8 a) {
    s16x8 r;
#pragma unroll
    for (int i = 0; i < 8; i++) {
        float v = bf2f((u16)a[i]);
        v = 0.5f * v * (1.f + erff(v * 0.70710678118654752f));
        r[i] = (short)f2bf(v);
    }
    return r;
}

// ---------------- zero fill ----------------
__global__ void k_zero_i(int* __restrict__ p, int n) {
    for (int i = blockIdx.x * 256 + threadIdx.x; i < n; i += gridDim.x * 256) p[i] = 0;
}

// ---------------- batched histogram of 3 dst arrays ----------------
__global__ void k_hist3(const int* __restrict__ d0, const int* __restrict__ d1, const int* __restrict__ d2,
                        int* __restrict__ cnt3) {
    int r = blockIdx.x >> 9;        // 0..2
    int b = blockIdx.x & 511;
    const int* dst = (r == 0) ? d0 : (r == 1) ? d1 : d2;
    int* cnt = cnt3 + (size_t)r * NT;
    for (int e = b * 256 + threadIdx.x; e < NE; e += 512 * 256)
        atomicAdd(&cnt[dst[e]], 1);
}

// ---------------- batched serial scans ----------------
__global__ __launch_bounds__(1024) void k_scan3(const int* __restrict__ cnt3,
                                                int* __restrict__ rp0, int* __restrict__ rp1, int* __restrict__ rp2) {
    int r = blockIdx.x;
    const int* cnt = cnt3 + (size_t)r * NT;
    int* rp = (r == 0) ? rp0 : (r == 1) ? rp1 : rp2;
    int n = (r == 1) ? NV : NT;
    __shared__ int wsum[16];
    __shared__ int carry_s;
    int t = threadIdx.x, lane = t & 63, wv = t >> 6;
    if (t == 0) { carry_s = 0; rp[0] = 0; }
    __syncthreads();
    for (int base = 0; base < n; base += 1024) {
        int v = (base + t < n) ? cnt[base + t] : 0;
        int x = v;
#pragma unroll
        for (int off = 1; off < 64; off <<= 1) {
            int y = __shfl_up(x, off, 64);
            if (lane >= off) x += y;
        }
        if (lane == 63) wsum[wv] = x;
        __syncthreads();
        if (wv == 0 && lane < 16) {
            int s = wsum[lane];
#pragma unroll
            for (int off = 1; off < 16; off <<= 1) {
                int y = __shfl_up(s, off, 64);
                if (lane >= off) s += y;
            }
            wsum[lane] = s;
        }
        __syncthreads();
        int prefix = carry_s + (wv > 0 ? wsum[wv - 1] : 0);
        if (base + t < n) rp[base + t + 1] = prefix + x;
        __syncthreads();
        if (t == 0) carry_s += wsum[15];
        __syncthreads();
    }
}

// ---------------- batched fill copy ----------------
__global__ void k_copy3(const int* __restrict__ rp0, const int* __restrict__ rp1, const int* __restrict__ rp2,
                        int* __restrict__ fill3) {
    int r = blockIdx.x >> 8;
    int b = blockIdx.x & 255;
    const int* rp = (r == 0) ? rp0 : (r == 1) ? rp1 : rp2;
    int n = (r == 1) ? NV : NT;
    int* fill = fill3 + (size_t)r * NT;
    for (int i = b * 256 + threadIdx.x; i < n; i += 256 * 256) fill[i] = rp[i];
}

// ---------------- batched scatter ----------------
__global__ void k_scatter3(const int* __restrict__ d0, const int* __restrict__ s0,
                           const int* __restrict__ d1, const int* __restrict__ s1,
                           const int* __restrict__ d2, const int* __restrict__ s2,
                           int* __restrict__ fill3,
                           int* __restrict__ es0, int* __restrict__ es1, int* __restrict__ es2) {
    int r = blockIdx.x >> 9;
    int b = blockIdx.x & 511;
    const int* dst = (r == 0) ? d0 : (r == 1) ? d1 : d2;
    const int* src = (r == 0) ? s0 : (r == 1) ? s1 : s2;
    int* fill = fill3 + (size_t)r * NT;
    int* es = (r == 0) ? es0 : (r == 1) ? es1 : es2;
    for (int e = b * 256 + threadIdx.x; e < NE; e += 512 * 256) {
        int d = dst[e];
        int p = atomicAdd(&fill[d], 1);
        es[p] = src[e];
    }
}

// ---------------- input projection ----------------
__global__ __launch_bounds__(256) void k_in_proj(const float* __restrict__ X, const float* __restrict__ W,
                          const float* __restrict__ b, u16* __restrict__ Y, int N) {
    const int NPB = 16;
    __shared__ float xs[NPB][FIN];
    int n0 = blockIdx.x * NPB;
    int t = threadIdx.x;
    for (int idx = t; idx < NPB * FIN; idx += 256) {
        int i = idx >> 6, c = idx & 63;
        int n = n0 + i;
        xs[i][c] = (n < N) ? X[(size_t)n * FIN + c] : 0.f;
    }
    __syncthreads();
    float acc[NPB];
#pragma unroll
    for (int i = 0; i < NPB; i++) acc[i] = 0.f;
    for (int c = 0; c < FIN; c++) {
        float w = W[c * HID + t];
#pragma unroll
        for (int i = 0; i < NPB; i++) acc[i] += xs[i][c] * w;
    }
    float bb = b[t];
    for (int i = 0; i < NPB; i++) {
        int n = n0 + i;
        if (n < N) Y[(size_t)n * HID + t] = f2bf(fmaxf(acc[i] + bb, 0.f));
    }
}

// swizzle index for MFMA B fragment
__device__ __forceinline__ int swz_idx(int k, int n) {
    int ks = k >> 5, r = k & 31;
    int j = r & 7;
    int l = ((r >> 3) << 4) | (n & 15);
    int nt = n >> 4;
    return ((ks * 16 + nt) * 64 + l) * 8 + j;
}

// ---------------- dual fuse: k and v weight pairs in one launch (16 blocks) ----------------
__global__ __launch_bounds__(256) void k_fuse_w2(
        const float* __restrict__ Wk_, const float* __restrict__ bk_, const float* __restrict__ Rk,
        u16* __restrict__ WswK, float* __restrict__ bkO,
        const float* __restrict__ Wv_, const float* __restrict__ bv_, const float* __restrict__ Rv,
        u16* __restrict__ WswV, float* __restrict__ bvO) {
    int h = blockIdx.x & 7;
    int which = blockIdx.x >> 3;
    const float* W = which ? Wv_ : Wk_;
    const float* b = which ? bv_ : bk_;
    const float* R = which ? Rv : Rk;
    u16* Wsw = which ? WswV : WswK;
    float* bout = which ? bvO : bkO;
    __shared__ float sR[DH * DH];
    int t = threadIdx.x;
    for (int idx = t; idx < DH * DH; idx += 256) sR[idx] = R[h * DH * DH + idx];
    __syncthreads();
    int f = t & 31, c0 = t >> 5;
    for (int c = c0; c < HID; c += 8) {
        float acc = 0.f;
#pragma unroll
        for (int d = 0; d < DH; d++) acc += W[c * HID + h * DH + d] * sR[d * DH + f];
        Wsw[swz_idx(c, h * DH + f)] = f2bf(acc);
    }
    if (t < DH) {
        float acc = 0.f;
#pragma unroll
        for (int d = 0; d < DH; d++) acc += b[h * DH + d] * sR[d * DH + t];
        bout[h * DH + t] = acc;
    }
}

// ---------------- batched swizzle of 9 static weights ----------------
__global__ __launch_bounds__(256) void k_swz_multi(const float* __restrict__ Wq, const float* __restrict__ Wa,
                                                   const float* __restrict__ Ws1, u16* __restrict__ out) {
    int slot = blockIdx.x >> 8;
    int idx = ((blockIdx.x & 255) << 8) | threadIdx.x;
    const float* src = (slot < 4) ? (Wq + (size_t)slot * 65536)
                     : (slot < 8) ? (Wa + (size_t)(slot - 4) * 65536)
                                  : Ws1;
    int j = idx & 7, l = (idx >> 3) & 63, nt = (idx >> 9) & 15, ks = idx >> 13;
    int k = ks * 32 + (l >> 4) * 8 + j;
    int n = nt * 16 + (l & 15);
    out[(size_t)slot * 65536 + idx] = f2bf(src[k * HID + n]);
}

// ---------------- MFMA GEMM, slim-wave ----------------
// MODE 0: bf16+bias. MODE 1: f32, no bias. MODE 2: skip-mix bf16. MODE 3: bf16, no bias.
template <int MODE, int GELU>
__global__ __launch_bounds__(256) void k_mm(const u16* __restrict__ X, const u16* __restrict__ Wsw,
                                            const float* __restrict__ bias, void* __restrict__ Y,
                                            const float* __restrict__ skip_, int N) {
    int tid = threadIdx.x;
    int w = tid >> 6, lane = tid & 63;
    int r0 = blockIdx.x * 16;
    int rA = r0 + (lane & 15);
    int koffg = lane >> 4;
    s16x8 a[8];
    if (rA < N) {
        const s16x8* ap = (const s16x8*)(X + (size_t)rA * HID) + koffg;
#pragma unroll
        for (int ks = 0; ks < 8; ks++) a[ks] = ap[ks * 4];
    } else {
#pragma unroll
        for (int ks = 0; ks < 8; ks++) a[ks] = (s16x8){0, 0, 0, 0, 0, 0, 0, 0};
    }
    if (GELU) {
#pragma unroll
        for (int ks = 0; ks < 8; ks++) a[ks] = gelu8(a[ks]);
    }
    f32x4 acc[4];
#pragma unroll
    for (int nt = 0; nt < 4; nt++) acc[nt] = (f32x4){0.f, 0.f, 0.f, 0.f};
    const s16x8* wp = (const s16x8*)Wsw;
#pragma unroll
    for (int ks = 0; ks < 8; ks++) {
        const s16x8* wq = wp + (size_t)ks * 16 * 64 + lane;
#pragma unroll
        for (int nt = 0; nt < 4; nt++) {
            s16x8 b = wq[(w * 4 + nt) * 64];
            acc[nt] = __builtin_amdgcn_mfma_f32_16x16x32_bf16(a[ks], b, acc[nt], 0, 0, 0);
        }
    }
    int colb = lane & 15;
    int rowb = r0 + koffg * 4;
    float beta = 0.f, ombeta = 0.f;
    if (MODE == 2) { beta = 1.f / (1.f + expf(-skip_[0])); ombeta = 1.f - beta; }
#pragma unroll
    for (int nt = 0; nt < 4; nt++) {
        int col = w * 64 + nt * 16 + colb;
        float bb = (MODE == 1 || MODE == 3) ? 0.f : bias[col];
#pragma unroll
        for (int j = 0; j < 4; j++) {
            int row = rowb + j;
            if (row < N) {
                float v = acc[nt][j] + bb;
                if (MODE == 0 || MODE == 3) {
                    ((u16*)Y)[(size_t)row * HID + col] = f2bf(v);
                } else if (MODE == 1) {
                    ((float*)Y)[(size_t)row * HID + col] = v;
                } else {
                    u16* hp = (u16*)Y + (size_t)row * HID + col;
                    *hp = f2bf(beta * v + ombeta * bf2f(*hp));
                }
            }
        }
    }
}

// ---------------- fused ht-update + tpart GEMM (layer 1 step G) ----------------
__global__ __launch_bounds__(256) void k_mm_gt(const u16* __restrict__ agg, const u16* __restrict__ WaSw,
                                               const float* __restrict__ ba_, const float* __restrict__ skip_,
                                               const u16* __restrict__ ht_old, const u16* __restrict__ Ws1Sw,
                                               u16* __restrict__ tpart, int N) {
    __shared__ u16 sH[16][264];
    int tid = threadIdx.x;
    int w = tid >> 6, lane = tid & 63;
    int r0 = blockIdx.x * 16;
    int rA = r0 + (lane & 15);
    int koffg = lane >> 4;
    s16x8 a[8];
    {
        const s16x8* ap = (const s16x8*)(agg + (size_t)rA * HID) + koffg;
#pragma unroll
        for (int ks = 0; ks < 8; ks++) a[ks] = gelu8(ap[ks * 4]);
    }
    f32x4 acc[4];
#pragma unroll
    for (int nt = 0; nt < 4; nt++) acc[nt] = (f32x4){0.f, 0.f, 0.f, 0.f};
    const s16x8* wp = (const s16x8*)WaSw;
#pragma unroll
    for (int ks = 0; ks < 8; ks++) {
        const s16x8* wq = wp + (size_t)ks * 16 * 64 + lane;
#pragma unroll
        for (int nt = 0; nt < 4; nt++)
            acc[nt] = __builtin_amdgcn_mfma_f32_16x16x32_bf16(a[ks], wq[(w * 4 + nt) * 64], acc[nt], 0, 0, 0);
    }
    float beta = 1.f / (1.f + expf(-skip_[0])), ombeta = 1.f - beta;
    int colb = lane & 15;
    int rowl = koffg * 4;
#pragma unroll
    for (int nt = 0; nt < 4; nt++) {
        int col = w * 64 + nt * 16 + colb;
        float bb = ba_[col];
#pragma unroll
        for (int j = 0; j < 4; j++) {
            int row = r0 + rowl + j;
            float v = acc[nt][j] + bb;
            float o = beta * v + ombeta * bf2f(ht_old[(size_t)row * HID + col]);
            sH[rowl + j][col] = f2bf(o);
        }
    }
    __syncthreads();
    s16x8 a2[8];
#pragma unroll
    for (int ks = 0; ks < 8; ks++)
        a2[ks] = *(const s16x8*)&sH[lane & 15][ks * 32 + koffg * 8];
#pragma unroll
    for (int nt = 0; nt < 4; nt++) acc[nt] = (f32x4){0.f, 0.f, 0.f, 0.f};
    const s16x8* wp2 = (const s16x8*)Ws1Sw;
#pragma unroll
    for (int ks = 0; ks < 8; ks++) {
        const s16x8* wq = wp2 + (size_t)ks * 16 * 64 + lane;
#pragma unroll
        for (int nt = 0; nt < 4; nt++)
            acc[nt] = __builtin_amdgcn_mfma_f32_16x16x32_bf16(a2[ks], wq[(w * 4 + nt) * 64], acc[nt], 0, 0, 0);
    }
#pragma unroll
    for (int nt = 0; nt < 4; nt++) {
        int col = w * 64 + nt * 16 + colb;
#pragma unroll
        for (int j = 0; j < 4; j++) {
            int row = r0 + rowl + j;
            if (row < N) tpart[(size_t)row * HID + col] = f2bf(acc[nt][j]);
        }
    }
}

// ---------------- fused l0 hv-update + l1 r0 k/v projections (cross-layer) ----------------
// pass1: hv_new = beta*(gelu(aggv)@Wa0 + ba0) + (1-beta)*hv_old  -> global hv + LDS
// pass2: kA0 = LDS @ WkSw + bk ; pass3: vM0 = LDS @ WvSw + bv
__global__ __launch_bounds__(256) void k_mm_dv(const u16* __restrict__ aggv, const u16* __restrict__ WaSw,
                                               const float* __restrict__ ba_, const float* __restrict__ skip_,
                                               u16* __restrict__ hv,
                                               const u16* __restrict__ WkSw, const float* __restrict__ bkF,
                                               const u16* __restrict__ WvSw, const float* __restrict__ bvF,
                                               u16* __restrict__ kA0, u16* __restrict__ vM0, int N) {
    __shared__ u16 sH[16][264];
    int tid = threadIdx.x;
    int w = tid >> 6, lane = tid & 63;
    int r0 = blockIdx.x * 16;
    int rA = r0 + (lane & 15);
    int koffg = lane >> 4;
    s16x8 a[8];
    {
        const s16x8* ap = (const s16x8*)(aggv + (size_t)rA * HID) + koffg;
#pragma unroll
        for (int ks = 0; ks < 8; ks++) a[ks] = gelu8(ap[ks * 4]);
    }
    f32x4 acc[4];
#pragma unroll
    for (int nt = 0; nt < 4; nt++) acc[nt] = (f32x4){0.f, 0.f, 0.f, 0.f};
    const s16x8* wp = (const s16x8*)WaSw;
#pragma unroll
    for (int ks = 0; ks < 8; ks++) {
        const s16x8* wq = wp + (size_t)ks * 16 * 64 + lane;
#pragma unroll
        for (int nt = 0; nt < 4; nt++)
            acc[nt] = __builtin_amdgcn_mfma_f32_16x16x32_bf16(a[ks], wq[(w * 4 + nt) * 64], acc[nt], 0, 0, 0);
    }
    float beta = 1.f / (1.f + expf(-skip_[0])), ombeta = 1.f - beta;
    int colb = lane & 15;
    int rowl = koffg * 4;
#pragma unroll
    for (int nt = 0; nt < 4; nt++) {
        int col = w * 64 + nt * 16 + colb;
        float bb = ba_[col];
#pragma unroll
        for (int j = 0; j < 4; j++) {
            int row = r0 + rowl + j;
            float v = acc[nt][j] + bb;
            u16 o = f2bf(beta * v + ombeta * bf2f(hv[(size_t)row * HID + col]));
            hv[(size_t)row * HID + col] = o;   // global: post-l0 hv (for q8 / vpart_f)
            sH[rowl + j][col] = o;
        }
    }
    __syncthreads();
    s16x8 a2[8];
#pragma unroll
    for (int ks = 0; ks < 8; ks++)
        a2[ks] = *(const s16x8*)&sH[lane & 15][ks * 32 + koffg * 8];
#pragma unroll
    for (int pass = 0; pass < 2; pass++) {
        const u16* Wsw = pass ? WvSw : WkSw;
        const float* bias = pass ? bvF : bkF;
        u16* Y = pass ? vM0 : kA0;
#pragma unroll
        for (int nt = 0; nt < 4; nt++) acc[nt] = (f32x4){0.f, 0.f, 0.f, 0.f};
        const s16x8* wp2 = (const s16x8*)Wsw;
#pragma unroll
        for (int ks = 0; ks < 8; ks++) {
            const s16x8* wq = wp2 + (size_t)ks * 16 * 64 + lane;
#pragma unroll
            for (int nt = 0; nt < 4; nt++)
                acc[nt] = __builtin_amdgcn_mfma_f32_16x16x32_bf16(a2[ks], wq[(w * 4 + nt) * 64], acc[nt], 0, 0, 0);
        }
#pragma unroll
        for (int nt = 0; nt < 4; nt++) {
            int col = w * 64 + nt * 16 + colb;
            float bb = bias[col];
#pragma unroll
            for (int j = 0; j < 4; j++) {
                int row = r0 + rowl + j;
                if (row < N) Y[(size_t)row * HID + col] = f2bf(acc[nt][j] + bb);
            }
        }
    }
}

// ---------------- dual-B slim-wave MFMA GEMM ----------------
__global__ __launch_bounds__(256) void k_mm2(const u16* __restrict__ X,
                                             const u16* __restrict__ W1, const float* __restrict__ b1, u16* __restrict__ Y1,
                                             const u16* __restrict__ W2, const float* __restrict__ b2, u16* __restrict__ Y2,
                                             int N) {
    int tid = threadIdx.x;
    int w = tid >> 6, lane = tid & 63;
    int r0 = blockIdx.x * 16;
    int rA = r0 + (lane & 15);
    int koffg = lane >> 4;
    s16x8 a[8];
    if (rA < N) {
        const s16x8* ap = (const s16x8*)(X + (size_t)rA * HID) + koffg;
#pragma unroll
        for (int ks = 0; ks < 8; ks++) a[ks] = ap[ks * 4];
    } else {
#pragma unroll
        for (int ks = 0; ks < 8; ks++) a[ks] = (s16x8){0, 0, 0, 0, 0, 0, 0, 0};
    }
    int colb = lane & 15;
    int rowb = r0 + koffg * 4;
#pragma unroll
    for (int pass = 0; pass < 2; pass++) {
        const u16* Wsw = pass ? W2 : W1;
        const float* bias = pass ? b2 : b1;
        u16* Y = pass ? Y2 : Y1;
        f32x4 acc[4];
#pragma unroll
        for (int nt = 0; nt < 4; nt++) acc[nt] = (f32x4){0.f, 0.f, 0.f, 0.f};
        const s16x8* wp = (const s16x8*)Wsw;
#pragma unroll
        for (int ks = 0; ks < 8; ks++) {
            const s16x8* wq = wp + (size_t)ks * 16 * 64 + lane;
#pragma unroll
            for (int nt = 0; nt < 4; nt++) {
                s16x8 b = wq[(w * 4 + nt) * 64];
                acc[nt] = __builtin_amdgcn_mfma_f32_16x16x32_bf16(a[ks], b, acc[nt], 0, 0, 0);
            }
        }
#pragma unroll
        for (int nt = 0; nt < 4; nt++) {
            int col = w * 64 + nt * 16 + colb;
            float bb = bias[col];
#pragma unroll
            for (int j = 0; j < 4; j++) {
                int row = rowb + j;
                if (row < N) Y[(size_t)row * HID + col] = f2bf(acc[nt][j] + bb);
            }
        }
    }
}

// ---------------- triple-B slim-wave MFMA GEMM ----------------
__global__ __launch_bounds__(256) void k_mm3(const u16* __restrict__ X,
                                             const u16* __restrict__ W0, const float* __restrict__ b0, u16* __restrict__ Y0,
                                             const u16* __restrict__ W1, const float* __restrict__ b1, u16* __restrict__ Y1,
                                             const u16* __restrict__ W2, const float* __restrict__ b2, u16* __restrict__ Y2,
                                             int N) {
    int tid = threadIdx.x;
    int w = tid >> 6, lane = tid & 63;
    int r0 = blockIdx.x * 16;
    int rA = r0 + (lane & 15);
    int koffg = lane >> 4;
    s16x8 a[8];
    if (rA < N) {
        const s16x8* ap = (const s16x8*)(X + (size_t)rA * HID) + koffg;
#pragma unroll
        for (int ks = 0; ks < 8; ks++) a[ks] = ap[ks * 4];
    } else {
#pragma unroll
        for (int ks = 0; ks < 8; ks++) a[ks] = (s16x8){0, 0, 0, 0, 0, 0, 0, 0};
    }
    int colb = lane & 15;
    int rowb = r0 + koffg * 4;
#pragma unroll
    for (int pass = 0; pass < 3; pass++) {
        const u16* Wsw = (pass == 0) ? W0 : (pass == 1) ? W1 : W2;
        const float* bias = (pass == 0) ? b0 : (pass == 1) ? b1 : b2;
        u16* Y = (pass == 0) ? Y0 : (pass == 1) ? Y1 : Y2;
        f32x4 acc[4];
#pragma unroll
        for (int nt = 0; nt < 4; nt++) acc[nt] = (f32x4){0.f, 0.f, 0.f, 0.f};
        const s16x8* wp = (const s16x8*)Wsw;
#pragma unroll
        for (int ks = 0; ks < 8; ks++) {
            const s16x8* wq = wp + (size_t)ks * 16 * 64 + lane;
#pragma unroll
            for (int nt = 0; nt < 4; nt++) {
                s16x8 b = wq[(w * 4 + nt) * 64];
                acc[nt] = __builtin_amdgcn_mfma_f32_16x16x32_bf16(a[ks], b, acc[nt], 0, 0, 0);
            }
        }
#pragma unroll
        for (int nt = 0; nt < 4; nt++) {
            int col = w * 64 + nt * 16 + colb;
            float bb = bias[col];
#pragma unroll
            for (int j = 0; j < 4; j++) {
                int row = rowb + j;
                if (row < N) Y[(size_t)row * HID + col] = f2bf(acc[nt][j] + bb);
            }
        }
    }
}

// ---------------- online-softmax over one CSR, 2-deep prefetch ----------------
__device__ __forceinline__ void attn_pass(const u16* __restrict__ kA, const u16* __restrict__ vM,
                                          const int* __restrict__ es, int jb, int je,
                                          float q0, float q1, float q2, float q3, float ph, int lane4,
                                          float& o0, float& o1, float& o2, float& o3) {
    float m = -INFINITY, ss = 0.f, a0 = 0.f, a1 = 0.f, a2 = 0.f, a3 = 0.f;
    uint2 ku0 = {0, 0}, vu0 = {0, 0}, ku1 = {0, 0}, vu1 = {0, 0};
    if (jb < je) {
        int s = es[jb];
        ku0 = *(const uint2*)(kA + (size_t)s * HID + lane4);
        vu0 = *(const uint2*)(vM + (size_t)s * HID + lane4);
    }
    if (jb + 1 < je) {
        int s = es[jb + 1];
        ku1 = *(const uint2*)(kA + (size_t)s * HID + lane4);
        vu1 = *(const uint2*)(vM + (size_t)s * HID + lane4);
    }
    for (int j = jb; j < je; j++) {
        uint2 ku = ku0, vu = vu0;
        ku0 = ku1; vu0 = vu1;
        if (j + 2 < je) {
            int s = es[j + 2];
            ku1 = *(const uint2*)(kA + (size_t)s * HID + lane4);
            vu1 = *(const uint2*)(vM + (size_t)s * HID + lane4);
        }
        float k0, k1, k2, k3; up2(ku.x, k0, k1); up2(ku.y, k2, k3);
        float part = q0 * k0 + q1 * k1 + q2 * k2 + q3 * k3;
        part += __shfl_xor(part, 1, 64);
        part += __shfl_xor(part, 2, 64);
        part += __shfl_xor(part, 4, 64);
        float logit = part * ph;
        float nm = fmaxf(m, logit);
        float corr = expf(m - nm);
        float ee = expf(logit - nm);
        float v0, v1, v2, v3; up2(vu.x, v0, v1); up2(vu.y, v2, v3);
        ss = ss * corr + ee;
        a0 = a0 * corr + ee * v0; a1 = a1 * corr + ee * v1;
        a2 = a2 * corr + ee * v2; a3 = a3 * corr + ee * v3;
        m = nm;
    }
    float inv = 1.f / (ss + 1e-16f);
    o0 += a0 * inv; o1 += a1 * inv; o2 += a2 * inv; o3 += a3 * inv;
}

// ---------------- single-relation node attention (agg may alias q: safe, per-node rw) ------
__global__ __launch_bounds__(256) void k_node_attn(
        const u16* __restrict__ q, const u16* __restrict__ kA, const u16* __restrict__ vM,
        const int* __restrict__ rp, const int* __restrict__ es,
        const float* __restrict__ P, float scale,
        u16* __restrict__ agg, int Nd) {
    int node = blockIdx.x * 4 + (threadIdx.x >> 6);
    if (node >= Nd) return;
    int lane = threadIdx.x & 63;
    float ph = P[lane >> 3] * scale;
    uint2 qu = *(const uint2*)(q + (size_t)node * HID + lane * 4);
    float q0, q1, q2, q3; up2(qu.x, q0, q1); up2(qu.y, q2, q3);
    float o0 = 0.f, o1 = 0.f, o2 = 0.f, o3 = 0.f;
    attn_pass(kA, vM, es, rp[node], rp[node + 1], q0, q1, q2, q3, ph, lane * 4, o0, o1, o2, o3);
    u16* ap = agg + (size_t)node * HID + lane * 4;
    ap[0] = f2bf(o0); ap[1] = f2bf(o1); ap[2] = f2bf(o2); ap[3] = f2bf(o3);
}

// ---------------- 8-node attention into compact agg8 ----------------
__global__ __launch_bounds__(256) void k_attn8(
        const u16* __restrict__ q8, const u16* __restrict__ kA, const u16* __restrict__ vM,
        const int* __restrict__ rp, const int* __restrict__ es, const int* __restrict__ current,
        const float* __restrict__ P, float scale, u16* __restrict__ agg8) {
    int wv = blockIdx.x * 4 + (threadIdx.x >> 6);
    if (wv >= NC) return;
    int node = current[wv * 2];
    int lane = threadIdx.x & 63;
    int lane4 = lane * 4;
    float ph = P[lane >> 3] * scale;
    uint2 qu = *(const uint2*)(q8 + (size_t)wv * HID + lane4);
    float q0, q1, q2, q3; up2(qu.x, q0, q1); up2(qu.y, q2, q3);
    float o0 = 0.f, o1 = 0.f, o2 = 0.f, o3 = 0.f;
    attn_pass(kA, vM, es, rp[node], rp[node + 1], q0, q1, q2, q3, ph, lane4, o0, o1, o2, o3);
    u16* ap = agg8 + (size_t)wv * HID + lane4;
    ap[0] = f2bf(o0); ap[1] = f2bf(o1); ap[2] = f2bf(o2); ap[3] = f2bf(o3);
}

// ---------------- q rows for the 8 current nodes (f32 weights) ----------------
__global__ __launch_bounds__(256) void k_q8(const u16* __restrict__ hv, const int* __restrict__ current,
                                            const float* __restrict__ Wq_, const float* __restrict__ bq_,
                                            u16* __restrict__ q8) {
    __shared__ float row[HID];
    int t = threadIdx.x;
    for (int c = 0; c < NC; c++) {
        int n = current[c * 2];
        row[t] = bf2f(hv[(size_t)n * HID + t]);
        __syncthreads();
        float acc = 0.f;
        for (int i = 0; i < HID; i++) acc += row[i] * Wq_[i * HID + t];
        q8[c * HID + t] = f2bf(acc + bq_[t]);
        __syncthreads();
    }
}

// ---------------- dual-relation node attention (dst=t: r0 + r2, f32 sum) ----------------
__global__ __launch_bounds__(256) void k_node_attn2(
        const u16* __restrict__ q,
        const u16* __restrict__ kA0, const u16* __restrict__ vM0,
        const int* __restrict__ rp0, const int* __restrict__ es0, const float* __restrict__ P0,
        const u16* __restrict__ kA1, const u16* __restrict__ vM1,
        const int* __restrict__ rp1, const int* __restrict__ es1, const float* __restrict__ P1,
        float scale, u16* __restrict__ agg, int Nd) {
    int node = blockIdx.x * 4 + (threadIdx.x >> 6);
    if (node >= Nd) return;
    int lane = threadIdx.x & 63;
    int h = lane >> 3;
    int lane4 = lane * 4;
    float ph0 = P0[h] * scale, ph1 = P1[h] * scale;
    uint2 qu = *(const uint2*)(q + (size_t)node * HID + lane4);
    float q0, q1, q2, q3; up2(qu.x, q0, q1); up2(qu.y, q2, q3);
    float o0 = 0.f, o1 = 0.f, o2 = 0.f, o3 = 0.f;
    attn_pass(kA0, vM0, es0, rp0[node], rp0[node + 1], q0, q1, q2, q3, ph0, lane4, o0, o1, o2, o3);
    attn_pass(kA1, vM1, es1, rp1[node], rp1[node + 1], q0, q1, q2, q3, ph1, lane4, o0, o1, o2, o3);
    u16* ap = agg + (size_t)node * HID + lane4;
    ap[0] = f2bf(o0); ap[1] = f2bf(o1); ap[2] = f2bf(o2); ap[3] = f2bf(o3);
}

// ---------------- fused l=1 hv-update (8 rows) + vpart ----------------
__global__ __launch_bounds__(256) void k_vpart_f(
        const u16* __restrict__ agg8, const float* __restrict__ Wa_, const float* __restrict__ ba_,
        const float* __restrict__ skip_, const u16* __restrict__ hv, const int* __restrict__ current,
        const float* __restrict__ Ws1, const float* __restrict__ bs1, float* __restrict__ vpart) {
    __shared__ float sG[NC][HID];
    int t = threadIdx.x;
#pragma unroll
    for (int c = 0; c < NC; c++) {
        float x = bf2f(agg8[c * HID + t]);
        sG[c][t] = 0.5f * x * (1.f + erff(x * 0.70710678118654752f));
    }
    __syncthreads();
    float acc[NC];
#pragma unroll
    for (int c = 0; c < NC; c++) acc[c] = 0.f;
    for (int i = 0; i < HID; i++) {
        float wv_ = Wa_[i * HID + t];
#pragma unroll
        for (int c = 0; c < NC; c++) acc[c] += sG[c][i] * wv_;
    }
    float beta = 1.f / (1.f + expf(-skip_[0])), ombeta = 1.f - beta;
    float bb = ba_[t];
    __syncthreads();
#pragma unroll
    for (int c = 0; c < NC; c++) {
        int n = current[c * 2];
        float o = beta * (acc[c] + bb) + ombeta * bf2f(hv[(size_t)n * HID + t]);
        sG[c][t] = bf2f(f2bf(o));
    }
    __syncthreads();
    float acc2[NC];
#pragma unroll
    for (int c = 0; c < NC; c++) acc2[c] = 0.f;
    for (int i = 0; i < HID; i++) {
        float w1 = Ws1[(size_t)(HID + i) * HID + t];
#pragma unroll
        for (int c = 0; c < NC; c++) acc2[c] += sG[c][i] * w1;
    }
    float bs = bs1[t];
#pragma unroll
    for (int c = 0; c < NC; c++) vpart[c * HID + t] = acc2[c] + bs;
}

// ---------------- final: tpart bf16 ----------------
__global__ __launch_bounds__(256) void k_final(const u16* __restrict__ tpart, const float* __restrict__ vpart,
                        const float* __restrict__ Ws2, const float* __restrict__ bs2,
                        float* __restrict__ out) {
    __shared__ float vp[NC * HID];
    int t = threadIdx.x;
    for (int idx = t; idx < NC * HID; idx += 256) vp[idx] = vpart[idx];
    __syncthreads();
    int lane = t & 63, w = t >> 6;
    float w20[4], w21[4];
#pragma unroll
    for (int i = 0; i < 4; i++) {
        w20[i] = Ws2[(lane + 64 * i) * 2 + 0];
        w21[i] = Ws2[(lane + 64 * i) * 2 + 1];
    }
    float b0 = bs2[0], b1 = bs2[1];
    for (int n = blockIdx.x * 4 + w; n < NT; n += gridDim.x * 4) {
        float tp[4];
#pragma unroll
        for (int i = 0; i < 4; i++) tp[i] = bf2f(tpart[(size_t)n * HID + lane + 64 * i]);
#pragma unroll
        for (int c = 0; c < NC; c++) {
            float a0 = 0.f, a1 = 0.f;
#pragma unroll
            for (int i = 0; i < 4; i++) {
                float hm = fmaxf(tp[i] + vp[c * HID + lane + 64 * i], 0.f);
                a0 += hm * w20[i];
                a1 += hm * w21[i];
            }
#pragma unroll
            for (int off = 32; off >= 1; off >>= 1) {
                a0 += __shfl_xor(a0, off, 64);
                a1 += __shfl_xor(a1, off, 64);
            }
            if (lane == 0) {
                out[(size_t)c * NT + n] = a0 + b0;
                float z = a1 + b1;
                out[(size_t)NC * NT + (size_t)c * NT + n] = 1.f / (1.f + expf(-z));
            }
        }
    }
}

extern "C" void kernel_launch(void* const* d_in, const int* in_sizes, int n_in,
                              void* d_out, int out_size, void* d_ws, size_t ws_size,
                              hipStream_t stream) {
    (void)in_sizes; (void)n_in; (void)out_size;
    const float* x_v    = (const float*)d_in[0];
    const float* x_t    = (const float*)d_in[1];
    const int* ei_vt_s  = (const int*)d_in[2];
    const int* ei_vt_d  = (const int*)d_in[3];
    const int* ei_tv_s  = (const int*)d_in[4];
    const int* ei_tv_d  = (const int*)d_in[5];
    const int* ei_tt_s  = (const int*)d_in[6];
    const int* ei_tt_d  = (const int*)d_in[7];
    const int* current  = (const int*)d_in[8];
    const float* W_in_v = (const float*)d_in[9];
    const float* b_in_v = (const float*)d_in[10];
    const float* W_in_t = (const float*)d_in[11];
    const float* b_in_t = (const float*)d_in[12];
    const float* Wk     = (const float*)d_in[13];
    const float* bk     = (const float*)d_in[14];
    const float* Wq     = (const float*)d_in[15];
    const float* bq     = (const float*)d_in[16];
    const float* Wv     = (const float*)d_in[17];
    const float* bv     = (const float*)d_in[18];
    const float* Wa     = (const float*)d_in[19];
    const float* ba     = (const float*)d_in[20];
    const float* skip   = (const float*)d_in[21];
    const float* a_rel  = (const float*)d_in[22];
    const float* m_rel  = (const float*)d_in[23];
    const float* p_rel  = (const float*)d_in[24];
    const float* Ws1    = (const float*)d_in[25];
    const float* bs1    = (const float*)d_in[26];
    const float* Ws2    = (const float*)d_in[27];
    const float* bs2    = (const float*)d_in[28];

    char* p = (char*)d_ws;
    auto alloc = [&](size_t bytes) -> char* {
        char* r = p;
        p += (bytes + 255) & ~(size_t)255;
        return r;
    };
    u16* hv   = (u16*)alloc((size_t)NV * HID * 2);
    u16* ht   = (u16*)alloc((size_t)NT * HID * 2);
    u16* qb   = (u16*)alloc((size_t)NT * HID * 2);
    u16* qv   = (u16*)alloc((size_t)NV * HID * 2);   // l0: q_v, then in-place agg_v
    u16* kA   = (u16*)alloc((size_t)NT * HID * 2);   // reused as bf16 tpart by k_mm_gt
    u16* vM   = (u16*)alloc((size_t)NT * HID * 2);
    u16* kA0  = (u16*)alloc((size_t)NV * HID * 2);
    u16* vM0  = (u16*)alloc((size_t)NV * HID * 2);
    u16* agg  = (u16*)alloc((size_t)NT * HID * 2);
    int* rp_vt = (int*)alloc((size_t)(NT + 1) * 4);
    int* rp_tv = (int*)alloc((size_t)(NV + 1) * 4);
    int* rp_tt = (int*)alloc((size_t)(NT + 1) * 4);
    int* es_vt = (int*)alloc((size_t)NE * 4);
    int* es_tv = (int*)alloc((size_t)NE * 4);
    int* es_tt = (int*)alloc((size_t)NE * 4);
    int* cnt3  = (int*)alloc((size_t)3 * NT * 4);
    int* fill3 = (int*)alloc((size_t)3 * NT * 4);
    float* vp  = (float*)alloc((size_t)NC * HID * 4);
    u16* q8   = (u16*)alloc((size_t)NC * HID * 2);
    u16* agg8 = (u16*)alloc((size_t)NC * HID * 2);
    float* bkF = (float*)alloc(HID * 4);
    float* bvF = (float*)alloc(HID * 4);
    u16*  wswK = (u16*)alloc((size_t)HID * HID * 2);
    u16*  wswV = (u16*)alloc((size_t)HID * HID * 2);
    u16*  wswK2 = (u16*)alloc((size_t)HID * HID * 2);
    u16*  wswV2 = (u16*)alloc((size_t)HID * HID * 2);
    float* bkF2 = (float*)alloc(HID * 4);
    float* bvF2 = (float*)alloc(HID * 4);
    u16*  wswA = (u16*)alloc((size_t)9 * HID * HID * 2);
    if ((size_t)(p - (char*)d_ws) > ws_size) return;

    const float scale = 0.17677669529663687f;

    // ---- setup ----
    k_zero_i<<<256, 256, 0, stream>>>(cnt3, 3 * NT);
    k_hist3<<<3 * 512, 256, 0, stream>>>(ei_vt_d, ei_tv_d, ei_tt_d, cnt3);
    k_scan3<<<3, 1024, 0, stream>>>(cnt3, rp_vt, rp_tv, rp_tt);
    k_copy3<<<3 * 256, 256, 0, stream>>>(rp_vt, rp_tv, rp_tt, fill3);
    k_scatter3<<<3 * 512, 256, 0, stream>>>(ei_vt_d, ei_vt_s, ei_tv_d, ei_tv_s, ei_tt_d, ei_tt_s,
                                            fill3, es_vt, es_tv, es_tt);
    k_swz_multi<<<9 * 256, 256, 0, stream>>>(Wq, Wa, Ws1, wswA);
    k_in_proj<<<(NV + 15) / 16, 256, 0, stream>>>(x_v, W_in_v, b_in_v, hv, NV);
    k_in_proj<<<(NT + 15) / 16, 256, 0, stream>>>(x_t, W_in_t, b_in_t, ht, NT);

    const int GV = (NV + 15) / 16, GT = (NT + 15) / 16;
    const float* AR = a_rel; const float* MR = m_rel;
#define REL_W(l, r) (AR + (size_t)((l) * 3 + (r)) * NH * DH * DH)
#define REL_M(l, r) (MR + (size_t)((l) * 3 + (r)) * NH * DH * DH)
#define REL_P(l, r) (p_rel + (size_t)((l) * 3 + (r)) * NH)

    // ================= LAYER 0 =================
    // A. r0(l0): fused q_v + k + v from initial hv
    k_fuse_w2<<<2 * NH, 256, 0, stream>>>(Wk + 0 * 65536, bk + 0 * HID, REL_W(0, 0), wswK, bkF,
                                          Wv + 0 * 65536, bv + 0 * HID, REL_M(0, 0), wswV, bvF);
    k_mm3<<<GV, 256, 0, stream>>>(hv, wswA + 0 * 65536, bq + 0 * HID, qv, wswK, bkF, kA0, wswV, bvF, vM0, NV);
    // B. r1(l0): fused q_t + k + v from initial ht
    k_fuse_w2<<<2 * NH, 256, 0, stream>>>(Wk + 1 * 65536, bk + 1 * HID, REL_W(0, 1), wswK, bkF,
                                          Wv + 1 * 65536, bv + 1 * HID, REL_M(0, 1), wswV, bvF);
    k_mm3<<<GT, 256, 0, stream>>>(ht, wswA + 1 * 65536, bq + 1 * HID, qb, wswK, bkF, kA, wswV, bvF, vM, NT);
    // C. aggregate r1 -> qv IN PLACE (agg_v survives past F)
    k_node_attn<<<(NV + 3) / 4, 256, 0, stream>>>(qv, kA, vM, rp_tv, es_tv, REL_P(0, 1), scale, qv, NV);
    // E. r2(l0) projections from initial ht
    k_fuse_w2<<<2 * NH, 256, 0, stream>>>(Wk + 1 * 65536, bk + 1 * HID, REL_W(0, 2), wswK2, bkF2,
                                          Wv + 1 * 65536, bv + 1 * HID, REL_M(0, 2), wswV2, bvF2);
    k_mm2<<<GT, 256, 0, stream>>>(ht, wswK2, bkF2, kA, wswV2, bvF2, vM, NT);
    // F. combined dst=t aggregation
    k_node_attn2<<<(NT + 3) / 4, 256, 0, stream>>>(qb, kA0, vM0, rp_vt, es_vt, REL_P(0, 0),
                                                   kA, vM, rp_tt, es_tt, REL_P(0, 2), scale, agg, NT);
    // G. ht update (l0)
    k_mm<2, 1><<<GT, 256, 0, stream>>>(agg, wswA + (size_t)(4 + 1) * 65536, ba + 1 * HID, ht, skip + 1, NT);

    // ===== cross-layer: hv update (l0, deferred D) fused with l1-r0 k/v projections =====
    k_fuse_w2<<<2 * NH, 256, 0, stream>>>(Wk + 2 * 65536, bk + 2 * HID, REL_W(1, 0), wswK, bkF,
                                          Wv + 2 * 65536, bv + 2 * HID, REL_M(1, 0), wswV, bvF);
    k_mm_dv<<<GV, 256, 0, stream>>>(qv /*agg_v*/, wswA + (size_t)(4 + 0) * 65536, ba + 0 * HID, skip + 0,
                                    hv, wswK, bkF, wswV, bvF, kA0, vM0, NV);
    k_q8<<<1, 256, 0, stream>>>(hv, current, Wq + (size_t)2 * 65536, bq + 2 * HID, q8);

    // ================= LAYER 1 =================
    // B. r1(l1): fused q_t + k + v from post-l0 ht
    k_fuse_w2<<<2 * NH, 256, 0, stream>>>(Wk + 3 * 65536, bk + 3 * HID, REL_W(1, 1), wswK, bkF,
                                          Wv + 3 * 65536, bv + 3 * HID, REL_M(1, 1), wswV, bvF);
    k_mm3<<<GT, 256, 0, stream>>>(ht, wswA + 3 * 65536, bq + 3 * HID, qb, wswK, bkF, kA, wswV, bvF, vM, NT);
    // C. 8-node aggregation (dst=v live set)
    k_attn8<<<2, 256, 0, stream>>>(q8, kA, vM, rp_tv, es_tv, current, REL_P(1, 1), scale, agg8);
    // E. r2(l1) projections
    k_fuse_w2<<<2 * NH, 256, 0, stream>>>(Wk + 3 * 65536, bk + 3 * HID, REL_W(1, 2), wswK2, bkF2,
                                          Wv + 3 * 65536, bv + 3 * HID, REL_M(1, 2), wswV2, bvF2);
    k_mm2<<<GT, 256, 0, stream>>>(ht, wswK2, bkF2, kA, wswV2, bvF2, vM, NT);
    // F. combined dst=t aggregation
    k_node_attn2<<<(NT + 3) / 4, 256, 0, stream>>>(qb, kA0, vM0, rp_vt, es_vt, REL_P(1, 0),
                                                   kA, vM, rp_tt, es_tt, REL_P(1, 2), scale, agg, NT);
    // G. fused ht-update + tpart (tpart -> kA)
    k_mm_gt<<<GT, 256, 0, stream>>>(agg, wswA + (size_t)(4 + 3) * 65536, ba + 3 * HID, skip + 3,
                                    ht, wswA + (size_t)8 * 65536, kA, NT);

    // ---- epilogue ----
    k_vpart_f<<<1, 256, 0, stream>>>(agg8, Wa + (size_t)2 * 65536, ba + 2 * HID, skip + 2,
                                     hv, current, Ws1, bs1, vp);
    k_final<<<2048, 256, 0, stream>>>(kA /*tpart*/, vp, Ws2, bs2, (float*)d_out);
}